// Round 3
// baseline (613.137 us; speedup 1.0000x reference)
//
#include <hip/hip_runtime.h>
#include <hip/hip_bf16.h>

#define B 4
#define S 2048
#define D 128
#define H 4
#define HD 32
#define D2 256
#define BSD (B*S*D)   // 1048576

__device__ __forceinline__ float silu_f(float z){ return z / (1.f + __expf(-z)); }

// ---------------------------------------------------------------------------
// Kernel 1: q = silu(x@Wq+bq), k = silu(x@Wk+bk), v = silu(x@Wv+bv), u = x@Wu+bu
// 8 rows per block, 256 threads. col space: [0,128)=q [128,256)=k [256,384)=v [384,640)=u
// ---------------------------------------------------------------------------
__global__ __launch_bounds__(256) void k_qkvu(
    const float* __restrict__ x,
    const float* __restrict__ Wq, const float* __restrict__ bq,
    const float* __restrict__ Wk, const float* __restrict__ bk,
    const float* __restrict__ Wv, const float* __restrict__ bv,
    const float* __restrict__ Wu, const float* __restrict__ bu,
    float* __restrict__ q, float* __restrict__ k, float* __restrict__ v,
    float* __restrict__ u)
{
    __shared__ float xs[8][D];
    const int row0 = blockIdx.x * 8;
    const int tid  = threadIdx.x;
    #pragma unroll
    for (int i = 0; i < 4; ++i) {
        int idx = tid + i * 256;                 // 0..1023
        xs[idx >> 7][idx & 127] = x[row0 * D + idx];
    }
    __syncthreads();
    for (int p = 0; p < 3; ++p) {
        int col = tid + p * 256;
        if (col >= 640) break;
        const float* W; const float* bias; float* dst; int cn; int stride; bool act;
        if (col < 128)      { W = Wq; bias = bq; dst = q; cn = col;       stride = D;  act = true; }
        else if (col < 256) { W = Wk; bias = bk; dst = k; cn = col - 128; stride = D;  act = true; }
        else if (col < 384) { W = Wv; bias = bv; dst = v; cn = col - 256; stride = D;  act = true; }
        else                { W = Wu; bias = bu; dst = u; cn = col - 384; stride = D2; act = false; }
        float bcol = bias[cn];
        float acc[8];
        #pragma unroll
        for (int r = 0; r < 8; ++r) acc[r] = bcol;
        for (int i = 0; i < D; ++i) {
            float w = W[i * stride + cn];
            #pragma unroll
            for (int r = 0; r < 8; ++r) acc[r] += xs[r][i] * w;
        }
        #pragma unroll
        for (int r = 0; r < 8; ++r) {
            float o = act ? silu_f(acc[r]) : acc[r];
            dst[(row0 + r) * stride + cn] = o;
        }
    }
}

// ---------------------------------------------------------------------------
// Kernel 2a: pos_attn[b,n,d] = sum_m pos_w[S-1+m-n] * v[b,m,d]   (full m range)
// grid (64 n-tiles of 32, B). Writes a[...,128:256].
// thread: d0 = tid&31 (4 d's, stride 32), g = tid>>5 (4 n's: g*4+i)
// ---------------------------------------------------------------------------
__global__ __launch_bounds__(256) void k_pos(
    const float* __restrict__ pos_w, const float* __restrict__ v,
    float* __restrict__ a)
{
    const int n0 = blockIdx.x * 32;
    const int b  = blockIdx.y;
    __shared__ float pw[2080];                   // window: pos_w[2016-n0 .. 2016-n0+2078]
    __shared__ float vs[64][D];
    const int tid = threadIdx.x;
    const int base = 2016 - n0;                  // in [0, 2016]; base+2078 <= 4094
    for (int i = tid; i < 2079; i += 256) pw[i] = pos_w[base + i];
    const int d0 = tid & 31;
    const int g  = tid >> 5;                     // 0..7
    float acc[4][4];
    #pragma unroll
    for (int i = 0; i < 4; ++i)
        #pragma unroll
        for (int j = 0; j < 4; ++j) acc[i][j] = 0.f;

    for (int mt = 0; mt < 32; ++mt) {
        const int mbase = mt * 64;
        __syncthreads();
        #pragma unroll
        for (int i = 0; i < 32; ++i) {
            int idx = tid + i * 256;             // 0..8191
            vs[idx >> 7][idx & 127] = v[(b * S + mbase + (idx >> 7)) * D + (idx & 127)];
        }
        __syncthreads();
        for (int mm = 0; mm < 64; ++mm) {
            int m = mbase + mm;
            float vv[4];
            #pragma unroll
            for (int j = 0; j < 4; ++j) vv[j] = vs[mm][d0 + 32 * j];
            #pragma unroll
            for (int i = 0; i < 4; ++i) {
                // pw index = (S-1 + m - n) - base = 31 + m - (g*4+i), in [0,2078]
                float w = pw[31 + m - (g * 4 + i)];
                #pragma unroll
                for (int j = 0; j < 4; ++j) acc[i][j] += w * vv[j];
            }
        }
    }
    #pragma unroll
    for (int i = 0; i < 4; ++i) {
        int row = b * S + n0 + g * 4 + i;
        #pragma unroll
        for (int j = 0; j < 4; ++j)
            a[row * D2 + D + d0 + 32 * j] = acc[i][j];
    }
}

// ---------------------------------------------------------------------------
// Kernel 2b: causal self-attention with weight = silu((q.k/sqrt(hd))^2)
// grid (32 n-tiles of 64, H, B). silu(0)=0 so no mask state needed.
// Writes a[...,0:128].
// ---------------------------------------------------------------------------
__global__ __launch_bounds__(256) void k_attn(
    const float* __restrict__ q, const float* __restrict__ k,
    const float* __restrict__ v, float* __restrict__ a)
{
    const int n0 = blockIdx.x * 64;
    const int h  = blockIdx.y;
    const int b  = blockIdx.z;
    __shared__ float qs[64][HD + 1];
    __shared__ float ks[64][HD + 1];
    __shared__ float vs[64][HD + 1];
    __shared__ float sc[64][65];
    const int tid = threadIdx.x;
    #pragma unroll
    for (int i = 0; i < 8; ++i) {
        int idx = tid + i * 256;                 // 0..2047
        qs[idx >> 5][idx & 31] = q[(b * S + n0 + (idx >> 5)) * D + h * HD + (idx & 31)];
    }
    const int d0 = tid & 31;
    const int g  = tid >> 5;
    float oacc[8];
    #pragma unroll
    for (int i = 0; i < 8; ++i) oacc[i] = 0.f;
    const int tn = tid & 15, tm = tid >> 4;

    for (int m0 = 0; m0 <= n0; m0 += 64) {
        __syncthreads();
        #pragma unroll
        for (int i = 0; i < 8; ++i) {
            int idx = tid + i * 256;
            int r = idx >> 5, c = idx & 31;
            ks[r][c] = k[(b * S + m0 + r) * D + h * HD + c];
            vs[r][c] = v[(b * S + m0 + r) * D + h * HD + c];
        }
        __syncthreads();
        // scores: each thread computes a 4x4 patch at (tn*4, tm*4)
        float s[4][4];
        #pragma unroll
        for (int i = 0; i < 4; ++i)
            #pragma unroll
            for (int j = 0; j < 4; ++j) s[i][j] = 0.f;
        for (int c = 0; c < HD; ++c) {
            float qv[4], kv[4];
            #pragma unroll
            for (int i = 0; i < 4; ++i) qv[i] = qs[tn * 4 + i][c];
            #pragma unroll
            for (int j = 0; j < 4; ++j) kv[j] = ks[tm * 4 + j][c];
            #pragma unroll
            for (int i = 0; i < 4; ++i)
                #pragma unroll
                for (int j = 0; j < 4; ++j) s[i][j] += qv[i] * kv[j];
        }
        const bool diag = (m0 == n0);
        #pragma unroll
        for (int i = 0; i < 4; ++i) {
            int n = tn * 4 + i;
            #pragma unroll
            for (int j = 0; j < 4; ++j) {
                int m = tm * 4 + j;
                float sv = s[i][j] * 0.17677669529663687f;   // 1/sqrt(32)
                float w  = silu_f(sv * sv);
                if (diag && m > n) w = 0.f;
                sc[n][m] = w;
            }
        }
        __syncthreads();
        for (int mm = 0; mm < 64; ++mm) {
            float vv = vs[mm][d0];
            #pragma unroll
            for (int i = 0; i < 8; ++i) oacc[i] += sc[g * 8 + i][mm] * vv;
        }
    }
    #pragma unroll
    for (int i = 0; i < 8; ++i) {
        int n = n0 + g * 8 + i;
        a[(b * S + n) * D2 + h * HD + d0] = oacc[i];
    }
}

// ---------------------------------------------------------------------------
// Kernel 3: LayerNorm(a) * u; out = relu(h@Wf + bf) + x. 4 rows/block.
// ---------------------------------------------------------------------------
__global__ __launch_bounds__(256) void k_final(
    const float* __restrict__ a, const float* __restrict__ u,
    const float* __restrict__ gamma, const float* __restrict__ beta,
    const float* __restrict__ Wf, const float* __restrict__ bfb,
    const float* __restrict__ x, float* __restrict__ out)
{
    __shared__ float hs[4][D2];
    __shared__ float red[2][4];
    __shared__ float part[2][4][D];
    const int tid  = threadIdx.x;
    const int row0 = blockIdx.x * 4;
    const int wave = tid >> 6, lane = tid & 63;
    const float gam = gamma[tid];
    const float bet = beta[tid];
    for (int r = 0; r < 4; ++r) {
        const int row = row0 + r;
        float av = a[row * D2 + tid];
        float s1 = av, s2 = av * av;
        #pragma unroll
        for (int off = 32; off > 0; off >>= 1) {
            s1 += __shfl_down(s1, off);
            s2 += __shfl_down(s2, off);
        }
        if (lane == 0) { red[0][wave] = s1; red[1][wave] = s2; }
        __syncthreads();
        float sum = red[0][0] + red[0][1] + red[0][2] + red[0][3];
        float sq  = red[1][0] + red[1][1] + red[1][2] + red[1][3];
        float mu  = sum * (1.f / 256.f);
        float var = sq * (1.f / 256.f) - mu * mu;
        float rs  = rsqrtf(var + 1e-3f);
        float an  = (av - mu) * rs * gam + bet;
        hs[r][tid] = u[row * D2 + tid] * an;
        __syncthreads();
    }
    const int d = tid & 127, half = tid >> 7;
    float acc[4] = {0.f, 0.f, 0.f, 0.f};
    for (int j = 0; j < 128; ++j) {
        int jj = half * 128 + j;
        float w = Wf[jj * D + d];
        #pragma unroll
        for (int r = 0; r < 4; ++r) acc[r] += hs[r][jj] * w;
    }
    #pragma unroll
    for (int r = 0; r < 4; ++r) part[half][r][d] = acc[r];
    __syncthreads();
    if (half == 0) {
        float bfv = bfb[d];
        #pragma unroll
        for (int r = 0; r < 4; ++r) {
            int row = row0 + r;
            float o = part[0][r][d] + part[1][r][d] + bfv;
            o = fmaxf(o, 0.f);
            o += x[row * D + d];
            out[row * D + d] = o;
        }
    }
}

// ---------------------------------------------------------------------------
extern "C" void kernel_launch(void* const* d_in, const int* in_sizes, int n_in,
                              void* d_out, int out_size, void* d_ws, size_t ws_size,
                              hipStream_t stream)
{
    const float* x     = (const float*)d_in[0];
    const float* Wq    = (const float*)d_in[1];
    const float* bq    = (const float*)d_in[2];
    const float* Wk    = (const float*)d_in[3];
    const float* bk    = (const float*)d_in[4];
    const float* Wv    = (const float*)d_in[5];
    const float* bv    = (const float*)d_in[6];
    const float* Wu    = (const float*)d_in[7];
    const float* bu    = (const float*)d_in[8];
    const float* pos_w = (const float*)d_in[9];
    const float* gamma = (const float*)d_in[10];
    const float* beta  = (const float*)d_in[11];
    const float* Wf    = (const float*)d_in[12];
    const float* bfb   = (const float*)d_in[13];
    float* out = (float*)d_out;

    // workspace: 7*BSD fp32 = 28 MB
    float* q = (float*)d_ws;        // BSD
    float* k = q + BSD;             // BSD
    float* v = k + BSD;             // BSD
    float* u = v + BSD;             // 2*BSD
    float* a = u + 2 * BSD;         // 2*BSD  (cols 0:128 self, 128:256 pos)

    k_qkvu <<<dim3(1024),     256, 0, stream>>>(x, Wq, bq, Wk, bk, Wv, bv, Wu, bu, q, k, v, u);
    k_pos  <<<dim3(64, B),    256, 0, stream>>>(pos_w, v, a);
    k_attn <<<dim3(32, H, B), 256, 0, stream>>>(q, k, v, a);
    k_final<<<dim3(2048),     256, 0, stream>>>(a, u, gamma, beta, Wf, bfb, x, out);
}

// Round 4
// 246.009 us; speedup vs baseline: 2.4923x; 2.4923x over previous
//
#include <hip/hip_runtime.h>
#include <hip/hip_bf16.h>

#define B 4
#define S 2048
#define D 128
#define H 4
#define HD 32
#define D2 256
#define BSD (B*S*D)   // 1048576

#define LDK 40   // ks LDS row stride (bf16 units), 80B = 16B-multiple
#define LDV 72   // vt LDS row stride (bf16 units), 144B = 16B-multiple
#define LDSC 68  // sc LDS row stride (fp32 units)

typedef __attribute__((ext_vector_type(8))) short bf16x8;
typedef __attribute__((ext_vector_type(4))) float f32x4;

__device__ __forceinline__ float silu_f(float z){ return z / (1.f + __expf(-z)); }
__device__ __forceinline__ short f2bfs(float f){
    __hip_bfloat16 h = __float2bfloat16(f);
    return *reinterpret_cast<short*>(&h);
}
__device__ __forceinline__ float bfs2f(short s){
    __hip_bfloat16 h = *reinterpret_cast<__hip_bfloat16*>(&s);
    return __bfloat162float(h);
}

// ---------------------------------------------------------------------------
// Kernel 1: projections. q,k -> bf16 row-major; v -> bf16 TRANSPOSED [B][D][S];
// u -> fp32 [B*S][2D]. 8 rows/block, 256 threads.
// col space: [0,128)=q [128,256)=k [256,384)=v [384,640)=u
// ---------------------------------------------------------------------------
__global__ __launch_bounds__(256) void k_qkvu(
    const float* __restrict__ x,
    const float* __restrict__ Wq, const float* __restrict__ bq,
    const float* __restrict__ Wk, const float* __restrict__ bk,
    const float* __restrict__ Wv, const float* __restrict__ bv,
    const float* __restrict__ Wu, const float* __restrict__ bu,
    short* __restrict__ qb, short* __restrict__ kb, short* __restrict__ vtb,
    float* __restrict__ u)
{
    __shared__ float xs[8][D];
    const int row0 = blockIdx.x * 8;
    const int tid  = threadIdx.x;
    #pragma unroll
    for (int i = 0; i < 4; ++i) {
        int idx = tid + i * 256;                 // 0..1023
        xs[idx >> 7][idx & 127] = x[row0 * D + idx];
    }
    __syncthreads();
    for (int p = 0; p < 3; ++p) {
        int col = tid + p * 256;
        if (col >= 640) break;
        const float* W; const float* bias; int cn; int stride; int kind;
        if (col < 128)      { W = Wq; bias = bq; cn = col;       stride = D;  kind = 0; }
        else if (col < 256) { W = Wk; bias = bk; cn = col - 128; stride = D;  kind = 1; }
        else if (col < 384) { W = Wv; bias = bv; cn = col - 256; stride = D;  kind = 2; }
        else                { W = Wu; bias = bu; cn = col - 384; stride = D2; kind = 3; }
        float bcol = bias[cn];
        float acc[8];
        #pragma unroll
        for (int r = 0; r < 8; ++r) acc[r] = bcol;
        for (int i = 0; i < D; ++i) {
            float w = W[i * stride + cn];
            #pragma unroll
            for (int r = 0; r < 8; ++r) acc[r] += xs[r][i] * w;
        }
        if (kind == 0 || kind == 1) {
            short* dst = (kind == 0) ? qb : kb;
            #pragma unroll
            for (int r = 0; r < 8; ++r)
                dst[(row0 + r) * D + cn] = f2bfs(silu_f(acc[r]));
        } else if (kind == 2) {
            // transposed store: vtb[(b*D + cn)*S + m], 8 consecutive m = 16B
            short tmp[8];
            #pragma unroll
            for (int r = 0; r < 8; ++r) tmp[r] = f2bfs(silu_f(acc[r]));
            int b  = row0 / S;
            int m0 = row0 % S;
            *(bf16x8*)(vtb + (b * D + cn) * S + m0) = *(bf16x8*)tmp;
        } else {
            #pragma unroll
            for (int r = 0; r < 8; ++r)
                u[(row0 + r) * D2 + cn] = acc[r];
        }
    }
}

// ---------------------------------------------------------------------------
// Kernel 2a (MFMA): pos_attn = Toeplitz(pos_w) @ v, no mask.
// grid (64 n-tiles of 32, B, 2 m-halves). Writes ap[z*BSD + ...] fp32.
// wave w: strip s=w>>1 (16 n-rows), d-half dh=w&1 (64 d-cols).
// ---------------------------------------------------------------------------
__global__ __launch_bounds__(256) void k_pos(
    const float* __restrict__ pos_w, const short* __restrict__ vtb,
    float* __restrict__ ap)
{
    const int n0 = blockIdx.x * 32;
    const int b  = blockIdx.y;
    const int z  = blockIdx.z;                   // m half
    __shared__ short pw[1056] __attribute__((aligned(16)));
    __shared__ short vt[128 * LDV] __attribute__((aligned(16)));
    const int tid  = threadIdx.x;
    const int w    = tid >> 6;
    const int lane = tid & 63;
    const int q16  = lane >> 4;
    const int l15  = lane & 15;
    const int s    = w >> 1;
    const int dh   = w & 1;

    // pw window: pos_w[base_g + i], i in [0,1055)
    const int base_g = 2016 + z * 1024 - n0;     // in [0, 3040]; +1054 <= 4094
    for (int i = tid; i < 1055; i += 256) pw[i] = f2bfs(pos_w[base_g + i]);

    f32x4 acc[4];
    #pragma unroll
    for (int dt = 0; dt < 4; ++dt) acc[dt] = (f32x4){0.f, 0.f, 0.f, 0.f};

    for (int mt = 0; mt < 16; ++mt) {
        __syncthreads();
        #pragma unroll
        for (int i = 0; i < 4; ++i) {
            int e = tid + i * 256;               // 0..1023
            int d = e >> 3, m8 = e & 7;
            *(bf16x8*)(vt + d * LDV + m8 * 8) =
                *(const bf16x8*)(vtb + (b * D + d) * S + z * 1024 + mt * 64 + m8 * 8);
        }
        __syncthreads();
        #pragma unroll
        for (int kt = 0; kt < 2; ++kt) {
            // A-frag: rel[n=l15][m=q16*8+j] gathered from pw
            bf16x8 af;
            int idx0 = mt * 64 + kt * 32 + q16 * 8 + 31 - s * 16 - l15;  // in [0,1047]
            #pragma unroll
            for (int j = 0; j < 8; ++j) af[j] = pw[idx0 + j];
            #pragma unroll
            for (int dt = 0; dt < 4; ++dt) {
                bf16x8 bv = *(const bf16x8*)(vt + (dh * 64 + dt * 16 + l15) * LDV + kt * 32 + q16 * 8);
                acc[dt] = __builtin_amdgcn_mfma_f32_16x16x32_bf16(af, bv, acc[dt], 0, 0, 0);
            }
        }
    }
    float* dst = ap + z * BSD;
    const int nrow = n0 + s * 16 + q16 * 4;
    #pragma unroll
    for (int dt = 0; dt < 4; ++dt)
        #pragma unroll
        for (int r = 0; r < 4; ++r)
            dst[(b * S + nrow + r) * D + dh * 64 + dt * 16 + l15] = acc[dt][r];
}

// ---------------------------------------------------------------------------
// Kernel 2b (MFMA): causal attention, weight = silu((q.k/sqrt(32))^2).
// grid (32 n-tiles of 64, H, B); nt reversed so heavy blocks dispatch first.
// wave w = 16-row n-strip. Writes a_self fp32 [B*S][128].
// ---------------------------------------------------------------------------
__global__ __launch_bounds__(256) void k_attn(
    const short* __restrict__ qb, const short* __restrict__ kb,
    const short* __restrict__ vtb, float* __restrict__ a_self)
{
    const int nt = 31 - blockIdx.x;              // heavy first
    const int n0 = nt * 64;
    const int h  = blockIdx.y;
    const int b  = blockIdx.z;
    __shared__ short ks[64 * LDK] __attribute__((aligned(16)));
    __shared__ short vt[32 * LDV] __attribute__((aligned(16)));
    __shared__ float sc[4][16 * LDSC] __attribute__((aligned(16)));
    const int tid  = threadIdx.x;
    const int w    = tid >> 6;
    const int lane = tid & 63;
    const int q16  = lane >> 4;
    const int l15  = lane & 15;

    // q A-frag: q[n = n0+w*16+l15][k = q16*8+j], loaded once
    bf16x8 qfrag = *(const bf16x8*)(qb + (b * S + n0 + w * 16 + l15) * D + h * HD + q16 * 8);

    f32x4 o0 = {0.f, 0.f, 0.f, 0.f};
    f32x4 o1 = {0.f, 0.f, 0.f, 0.f};

    const int nm = nt + 1;
    for (int it = 0; it < nm; ++it) {
        const int m0 = it * 64;
        __syncthreads();
        {   // stage k tile [64 m][32 k] and v^T tile [32 d][64 m]
            int row = tid >> 2, c8 = tid & 3;
            *(bf16x8*)(ks + row * LDK + c8 * 8) =
                *(const bf16x8*)(kb + (b * S + m0 + row) * D + h * HD + c8 * 8);
            int d = tid >> 3, m8 = tid & 7;
            *(bf16x8*)(vt + d * LDV + m8 * 8) =
                *(const bf16x8*)(vtb + (b * D + h * HD + d) * S + m0 + m8 * 8);
        }
        __syncthreads();
        // scores + weight -> wave-private sc strip [16 n][64 m]
        const int n_gb = n0 + w * 16 + q16 * 4;
        #pragma unroll
        for (int t = 0; t < 4; ++t) {
            bf16x8 kf = *(const bf16x8*)(ks + (t * 16 + l15) * LDK + q16 * 8);
            f32x4 sacc = {0.f, 0.f, 0.f, 0.f};
            sacc = __builtin_amdgcn_mfma_f32_16x16x32_bf16(qfrag, kf, sacc, 0, 0, 0);
            const int m_g = m0 + t * 16 + l15;
            #pragma unroll
            for (int r = 0; r < 4; ++r) {
                float sv = sacc[r] * 0.17677669529663687f;   // 1/sqrt(32)
                float x2 = sv * sv;
                float wgt = silu_f(x2);
                if (m_g > n_gb + r) wgt = 0.f;
                sc[w][(q16 * 4 + r) * LDSC + t * 16 + l15] = wgt;
            }
        }
        // PV: A-frag P[n=l15][m=kt*32+q16*8+j] from sc; B-frag V^T[d][m] from vt
        #pragma unroll
        for (int kt = 0; kt < 2; ++kt) {
            const float* prow = &sc[w][l15 * LDSC + kt * 32 + q16 * 8];
            bf16x8 pf;
            #pragma unroll
            for (int j = 0; j < 8; ++j) pf[j] = f2bfs(prow[j]);
            bf16x8 v0 = *(const bf16x8*)(vt + l15 * LDV        + kt * 32 + q16 * 8);
            bf16x8 v1 = *(const bf16x8*)(vt + (16 + l15) * LDV + kt * 32 + q16 * 8);
            o0 = __builtin_amdgcn_mfma_f32_16x16x32_bf16(pf, v0, o0, 0, 0, 0);
            o1 = __builtin_amdgcn_mfma_f32_16x16x32_bf16(pf, v1, o1, 0, 0, 0);
        }
    }
    const int nrow = n0 + w * 16 + q16 * 4;
    #pragma unroll
    for (int r = 0; r < 4; ++r) {
        a_self[(b * S + nrow + r) * D + h * HD + l15]      = o0[r];
        a_self[(b * S + nrow + r) * D + h * HD + 16 + l15] = o1[r];
    }
}

// ---------------------------------------------------------------------------
// Kernel 3: a = concat(self, pos0+pos1); LayerNorm; h = u*a;
// out = relu(h@Wf + bf) + x. 4 rows/block.
// ---------------------------------------------------------------------------
__global__ __launch_bounds__(256) void k_final(
    const float* __restrict__ a_self, const float* __restrict__ ap,
    const float* __restrict__ u,
    const float* __restrict__ gamma, const float* __restrict__ beta,
    const float* __restrict__ Wf, const float* __restrict__ bfb,
    const float* __restrict__ x, float* __restrict__ out)
{
    __shared__ float hs[4][D2];
    __shared__ float red[2][4];
    __shared__ float part[2][4][D];
    const int tid  = threadIdx.x;
    const int row0 = blockIdx.x * 4;
    const int wave = tid >> 6, lane = tid & 63;
    const float gam = gamma[tid];
    const float bet = beta[tid];
    for (int r = 0; r < 4; ++r) {
        const int row = row0 + r;
        float av;
        if (tid < 128) av = a_self[row * D + tid];
        else           av = ap[row * D + (tid - 128)] + ap[BSD + row * D + (tid - 128)];
        float s1 = av, s2 = av * av;
        #pragma unroll
        for (int off = 32; off > 0; off >>= 1) {
            s1 += __shfl_down(s1, off);
            s2 += __shfl_down(s2, off);
        }
        if (lane == 0) { red[0][wave] = s1; red[1][wave] = s2; }
        __syncthreads();
        float sum = red[0][0] + red[0][1] + red[0][2] + red[0][3];
        float sq  = red[1][0] + red[1][1] + red[1][2] + red[1][3];
        float mu  = sum * (1.f / 256.f);
        float var = sq * (1.f / 256.f) - mu * mu;
        float rs  = rsqrtf(var + 1e-3f);
        float an  = (av - mu) * rs * gam + bet;
        hs[r][tid] = u[row * D2 + tid] * an;
        __syncthreads();
    }
    const int d = tid & 127, half = tid >> 7;
    float acc[4] = {0.f, 0.f, 0.f, 0.f};
    for (int j = 0; j < 128; ++j) {
        int jj = half * 128 + j;
        float w = Wf[jj * D + d];
        #pragma unroll
        for (int r = 0; r < 4; ++r) acc[r] += hs[r][jj] * w;
    }
    #pragma unroll
    for (int r = 0; r < 4; ++r) part[half][r][d] = acc[r];
    __syncthreads();
    if (half == 0) {
        float bfv = bfb[d];
        #pragma unroll
        for (int r = 0; r < 4; ++r) {
            int row = row0 + r;
            float o = part[0][r][d] + part[1][r][d] + bfv;
            o = fmaxf(o, 0.f);
            o += x[row * D + d];
            out[row * D + d] = o;
        }
    }
}

// ---------------------------------------------------------------------------
extern "C" void kernel_launch(void* const* d_in, const int* in_sizes, int n_in,
                              void* d_out, int out_size, void* d_ws, size_t ws_size,
                              hipStream_t stream)
{
    const float* x     = (const float*)d_in[0];
    const float* Wq    = (const float*)d_in[1];
    const float* bq    = (const float*)d_in[2];
    const float* Wk    = (const float*)d_in[3];
    const float* bk    = (const float*)d_in[4];
    const float* Wv    = (const float*)d_in[5];
    const float* bv    = (const float*)d_in[6];
    const float* Wu    = (const float*)d_in[7];
    const float* bu    = (const float*)d_in[8];
    const float* pos_w = (const float*)d_in[9];
    const float* gamma = (const float*)d_in[10];
    const float* beta  = (const float*)d_in[11];
    const float* Wf    = (const float*)d_in[12];
    const float* bfb   = (const float*)d_in[13];
    float* out = (float*)d_out;

    // workspace layout (26 MB total; 28 MB proven safe in round 3):
    char* p = (char*)d_ws;
    short* qb     = (short*)p;  p += (size_t)BSD * 2;        //  2 MB bf16 q
    short* kb     = (short*)p;  p += (size_t)BSD * 2;        //  2 MB bf16 k
    short* vtb    = (short*)p;  p += (size_t)BSD * 2;        //  2 MB bf16 v^T [B][D][S]
    float* u      = (float*)p;  p += (size_t)2 * BSD * 4;    //  8 MB fp32 u
    float* a_self = (float*)p;  p += (size_t)BSD * 4;        //  4 MB fp32 self-attn
    float* ap     = (float*)p;  p += (size_t)2 * BSD * 4;    //  8 MB fp32 pos partials x2

    k_qkvu <<<dim3(1024),     256, 0, stream>>>(x, Wq, bq, Wk, bk, Wv, bv, Wu, bu, qb, kb, vtb, u);
    k_pos  <<<dim3(64, B, 2), 256, 0, stream>>>(pos_w, vtb, ap);
    k_attn <<<dim3(32, H, B), 256, 0, stream>>>(qb, kb, vtb, a_self);
    k_final<<<dim3(2048),     256, 0, stream>>>(a_self, ap, u, gamma, beta, Wf, bfb, x, out);
}

// Round 5
// 182.758 us; speedup vs baseline: 3.3549x; 1.3461x over previous
//
#include <hip/hip_runtime.h>
#include <hip/hip_bf16.h>

#define B 4
#define S 2048
#define D 128
#define H 4
#define HD 32
#define D2 256
#define BSD (B*S*D)   // 1048576

#define LDK 40   // k LDS row stride (bf16), 80B
#define LDV 72   // v^T LDS row stride (bf16), 144B
#define LDSC 68  // sc LDS row stride (fp32), 272B
#define LDW 136  // k_qkvu LDS row stride (bf16), 272B

typedef __attribute__((ext_vector_type(8))) short bf16x8;
typedef __attribute__((ext_vector_type(4))) short bf16x4;
typedef __attribute__((ext_vector_type(4))) float f32x4;

__device__ __forceinline__ float silu_f(float z){ return z / (1.f + __expf(-z)); }
__device__ __forceinline__ short f2bfs(float f){
    __hip_bfloat16 h = __float2bfloat16(f);
    return *reinterpret_cast<short*>(&h);
}
__device__ __forceinline__ float bfs2f(short s){
    __hip_bfloat16 h = *reinterpret_cast<__hip_bfloat16*>(&s);
    return __bfloat162float(h);
}

// ---------------------------------------------------------------------------
// Kernel 0: transpose Wf [256 k][128 n] fp32 -> wft [128 n][256 k] bf16.
// ---------------------------------------------------------------------------
__global__ __launch_bounds__(256) void k_wft(
    const float* __restrict__ Wf, short* __restrict__ wft)
{
    const int n = blockIdx.x;        // 0..127
    const int k = threadIdx.x;       // 0..255
    wft[n * D2 + k] = f2bfs(Wf[k * D + n]);
}

// ---------------------------------------------------------------------------
// Kernel 1 (MFMA): projections. Block = 64 rows x 64-col segment.
// blockIdx.y (cs): 0-1=q, 2-3=k, 4-5=v(transposed out), 6-9=u(bf16 out).
// ---------------------------------------------------------------------------
__global__ __launch_bounds__(256) void k_qkvu(
    const float* __restrict__ x,
    const float* __restrict__ Wq, const float* __restrict__ bq,
    const float* __restrict__ Wk, const float* __restrict__ bk,
    const float* __restrict__ Wv, const float* __restrict__ bv,
    const float* __restrict__ Wu, const float* __restrict__ bu,
    short* __restrict__ qb, short* __restrict__ kb, short* __restrict__ vtb,
    short* __restrict__ ub)
{
    __shared__ short xs[64 * LDW] __attribute__((aligned(16)));
    __shared__ short wt[64 * LDW] __attribute__((aligned(16)));
    const int rt = blockIdx.x;
    const int cs = blockIdx.y;
    const int row0 = rt * 64;
    const int tid  = threadIdx.x;
    const int w    = tid >> 6;
    const int lane = tid & 63;
    const int q16  = lane >> 4;
    const int l15  = lane & 15;

    const float* W; const float* bias; int cn0; int wstride; int kind;
    if (cs < 2)      { W = Wq; bias = bq; cn0 = cs * 64;       wstride = D;  kind = 0; }
    else if (cs < 4) { W = Wk; bias = bk; cn0 = (cs - 2) * 64; wstride = D;  kind = 1; }
    else if (cs < 6) { W = Wv; bias = bv; cn0 = (cs - 4) * 64; wstride = D;  kind = 2; }
    else             { W = Wu; bias = bu; cn0 = (cs - 6) * 64; wstride = D2; kind = 3; }

    // stage X[64][128] fp32 -> bf16 LDS
    #pragma unroll
    for (int i = 0; i < 8; ++i) {
        int e = tid + i * 256;               // 0..2047
        int row = e >> 5, c4 = (e & 31) * 4;
        f32x4 xv = *(const f32x4*)(x + (row0 + row) * D + c4);
        short tmp[4];
        #pragma unroll
        for (int j = 0; j < 4; ++j) tmp[j] = f2bfs(xv[j]);
        *(bf16x4*)(xs + row * LDW + c4) = *(bf16x4*)tmp;
    }
    // stage W^T[64 n][128 k] bf16 LDS (coalesced global read, scalar LDS write)
    {
        const int j = tid & 63;
        #pragma unroll
        for (int i = 0; i < 32; ++i) {
            int kk = (tid >> 6) + i * 4;
            wt[j * LDW + kk] = f2bfs(W[kk * wstride + cn0 + j]);
        }
    }
    __syncthreads();

    f32x4 acc[4];
    #pragma unroll
    for (int ct = 0; ct < 4; ++ct) acc[ct] = (f32x4){0.f, 0.f, 0.f, 0.f};
    #pragma unroll
    for (int ks = 0; ks < 4; ++ks) {
        bf16x8 af = *(const bf16x8*)(xs + (w * 16 + l15) * LDW + ks * 32 + q16 * 8);
        #pragma unroll
        for (int ct = 0; ct < 4; ++ct) {
            bf16x8 bf_ = *(const bf16x8*)(wt + (ct * 16 + l15) * LDW + ks * 32 + q16 * 8);
            acc[ct] = __builtin_amdgcn_mfma_f32_16x16x32_bf16(af, bf_, acc[ct], 0, 0, 0);
        }
    }

    // epilogue: D rows m = w*16+q16*4+r, col c = ct*16+l15
    const int bb   = row0 / S;
    const int mloc = (row0 % S) + w * 16 + q16 * 4;
    #pragma unroll
    for (int ct = 0; ct < 4; ++ct) {
        const int c  = ct * 16 + l15;
        const float bcol = bias[cn0 + c];
        if (kind == 2) {
            short tmp[4];
            #pragma unroll
            for (int r = 0; r < 4; ++r) tmp[r] = f2bfs(silu_f(acc[ct][r] + bcol));
            *(bf16x4*)(vtb + (bb * D + cn0 + c) * S + mloc) = *(bf16x4*)tmp;
        } else if (kind == 3) {
            #pragma unroll
            for (int r = 0; r < 4; ++r)
                ub[(row0 + w * 16 + q16 * 4 + r) * D2 + cn0 + c] = f2bfs(acc[ct][r] + bcol);
        } else {
            short* dst = (kind == 0) ? qb : kb;
            #pragma unroll
            for (int r = 0; r < 4; ++r)
                dst[(row0 + w * 16 + q16 * 4 + r) * D + cn0 + c] = f2bfs(silu_f(acc[ct][r] + bcol));
        }
    }
}

// ---------------------------------------------------------------------------
// Kernel 2a (MFMA): pos_attn = Toeplitz(pos_w) @ v, no mask.
// grid (64 n-tiles of 32, B, 2 m-halves). Writes ap[z*BSD + ...] fp32.
// ---------------------------------------------------------------------------
__global__ __launch_bounds__(256) void k_pos(
    const float* __restrict__ pos_w, const short* __restrict__ vtb,
    float* __restrict__ ap)
{
    const int n0 = blockIdx.x * 32;
    const int b  = blockIdx.y;
    const int z  = blockIdx.z;
    __shared__ short pw[1056] __attribute__((aligned(16)));
    __shared__ short vt[128 * LDV] __attribute__((aligned(16)));
    const int tid  = threadIdx.x;
    const int w    = tid >> 6;
    const int lane = tid & 63;
    const int q16  = lane >> 4;
    const int l15  = lane & 15;
    const int s    = w >> 1;
    const int dh   = w & 1;

    const int base_g = 2016 + z * 1024 - n0;
    for (int i = tid; i < 1055; i += 256) pw[i] = f2bfs(pos_w[base_g + i]);

    f32x4 acc[4];
    #pragma unroll
    for (int dt = 0; dt < 4; ++dt) acc[dt] = (f32x4){0.f, 0.f, 0.f, 0.f};

    for (int mt = 0; mt < 16; ++mt) {
        __syncthreads();
        #pragma unroll
        for (int i = 0; i < 4; ++i) {
            int e = tid + i * 256;
            int d = e >> 3, m8 = e & 7;
            *(bf16x8*)(vt + d * LDV + m8 * 8) =
                *(const bf16x8*)(vtb + (b * D + d) * S + z * 1024 + mt * 64 + m8 * 8);
        }
        __syncthreads();
        #pragma unroll
        for (int kt = 0; kt < 2; ++kt) {
            bf16x8 af;
            int idx0 = mt * 64 + kt * 32 + q16 * 8 + 31 - s * 16 - l15;
            #pragma unroll
            for (int j = 0; j < 8; ++j) af[j] = pw[idx0 + j];
            #pragma unroll
            for (int dt = 0; dt < 4; ++dt) {
                bf16x8 bv = *(const bf16x8*)(vt + (dh * 64 + dt * 16 + l15) * LDV + kt * 32 + q16 * 8);
                acc[dt] = __builtin_amdgcn_mfma_f32_16x16x32_bf16(af, bv, acc[dt], 0, 0, 0);
            }
        }
    }
    float* dst = ap + z * BSD;
    const int nrow = n0 + s * 16 + q16 * 4;
    #pragma unroll
    for (int dt = 0; dt < 4; ++dt)
        #pragma unroll
        for (int r = 0; r < 4; ++r)
            dst[(b * S + nrow + r) * D + dh * 64 + dt * 16 + l15] = acc[dt][r];
}

// ---------------------------------------------------------------------------
// Kernel 2b (MFMA): causal attention, weight = silu((q.k/sqrt(32))^2).
// grid (32 nt, H, B*2): z = m-range half; partial O -> as_part[z*BSD+...].
// ---------------------------------------------------------------------------
__global__ __launch_bounds__(256) void k_attn(
    const short* __restrict__ qb, const short* __restrict__ kb,
    const short* __restrict__ vtb, float* __restrict__ as_part)
{
    const int nt = 31 - blockIdx.x;              // heavy first
    const int n0 = nt * 64;
    const int h  = blockIdx.y;
    const int b  = blockIdx.z >> 1;
    const int zz = blockIdx.z & 1;
    __shared__ short ks[64 * LDK] __attribute__((aligned(16)));
    __shared__ short vt[32 * LDV] __attribute__((aligned(16)));
    __shared__ float sc[4][16 * LDSC] __attribute__((aligned(16)));
    const int tid  = threadIdx.x;
    const int w    = tid >> 6;
    const int lane = tid & 63;
    const int q16  = lane >> 4;
    const int l15  = lane & 15;

    bf16x8 qfrag = *(const bf16x8*)(qb + (b * S + n0 + w * 16 + l15) * D + h * HD + q16 * 8);

    f32x4 o0 = {0.f, 0.f, 0.f, 0.f};
    f32x4 o1 = {0.f, 0.f, 0.f, 0.f};

    const int nm    = nt + 1;
    const int half1 = (nm + 1) >> 1;
    const int it_lo = zz ? half1 : 0;
    const int it_hi = zz ? nm : half1;

    for (int it = it_lo; it < it_hi; ++it) {
        const int m0 = it * 64;
        __syncthreads();
        {
            int row = tid >> 2, c8 = tid & 3;
            *(bf16x8*)(ks + row * LDK + c8 * 8) =
                *(const bf16x8*)(kb + (b * S + m0 + row) * D + h * HD + c8 * 8);
            int d = tid >> 3, m8 = tid & 7;
            *(bf16x8*)(vt + d * LDV + m8 * 8) =
                *(const bf16x8*)(vtb + (b * D + h * HD + d) * S + m0 + m8 * 8);
        }
        __syncthreads();
        const int n_gb = n0 + w * 16 + q16 * 4;
        #pragma unroll
        for (int t = 0; t < 4; ++t) {
            bf16x8 kf = *(const bf16x8*)(ks + (t * 16 + l15) * LDK + q16 * 8);
            f32x4 sacc = {0.f, 0.f, 0.f, 0.f};
            sacc = __builtin_amdgcn_mfma_f32_16x16x32_bf16(qfrag, kf, sacc, 0, 0, 0);
            const int m_g = m0 + t * 16 + l15;
            #pragma unroll
            for (int r = 0; r < 4; ++r) {
                float sv = sacc[r] * 0.17677669529663687f;   // 1/sqrt(32)
                float x2 = sv * sv;
                float wgt = silu_f(x2);
                if (m_g > n_gb + r) wgt = 0.f;
                sc[w][(q16 * 4 + r) * LDSC + t * 16 + l15] = wgt;
            }
        }
        #pragma unroll
        for (int kt = 0; kt < 2; ++kt) {
            const float* prow = &sc[w][l15 * LDSC + kt * 32 + q16 * 8];
            f32x4 p0 = *(const f32x4*)(prow);
            f32x4 p1 = *(const f32x4*)(prow + 4);
            bf16x8 pf;
            #pragma unroll
            for (int j = 0; j < 4; ++j) { pf[j] = f2bfs(p0[j]); pf[4 + j] = f2bfs(p1[j]); }
            bf16x8 v0 = *(const bf16x8*)(vt + l15 * LDV        + kt * 32 + q16 * 8);
            bf16x8 v1 = *(const bf16x8*)(vt + (16 + l15) * LDV + kt * 32 + q16 * 8);
            o0 = __builtin_amdgcn_mfma_f32_16x16x32_bf16(pf, v0, o0, 0, 0, 0);
            o1 = __builtin_amdgcn_mfma_f32_16x16x32_bf16(pf, v1, o1, 0, 0, 0);
        }
    }
    float* dst = as_part + zz * BSD;
    const int nrow = n0 + w * 16 + q16 * 4;
    #pragma unroll
    for (int r = 0; r < 4; ++r) {
        dst[(b * S + nrow + r) * D + h * HD + l15]      = o0[r];
        dst[(b * S + nrow + r) * D + h * HD + 16 + l15] = o1[r];
    }
}

// ---------------------------------------------------------------------------
// Kernel 3: a = concat(self0+self1, pos0+pos1); LayerNorm; h = u*a;
// out = relu(h@Wf + bf) + x. 8 rows/block, Wf via pre-transposed bf16 wft.
// ---------------------------------------------------------------------------
__global__ __launch_bounds__(256) void k_final(
    const float* __restrict__ as_part, const float* __restrict__ ap,
    const short* __restrict__ ub, const short* __restrict__ wft,
    const float* __restrict__ gamma, const float* __restrict__ beta,
    const float* __restrict__ bfb,
    const float* __restrict__ x, float* __restrict__ out)
{
    __shared__ float hs[8][264];
    __shared__ float red[2][4];
    __shared__ float part[2][8][D];
    const int tid  = threadIdx.x;
    const int row0 = blockIdx.x * 8;
    const int wave = tid >> 6, lane = tid & 63;
    const float gam = gamma[tid];
    const float bet = beta[tid];
    for (int r = 0; r < 8; ++r) {
        const int row = row0 + r;
        float av;
        if (tid < 128) av = as_part[row * D + tid] + as_part[BSD + row * D + tid];
        else           av = ap[row * D + (tid - 128)] + ap[BSD + row * D + (tid - 128)];
        float s1 = av, s2 = av * av;
        #pragma unroll
        for (int off = 32; off > 0; off >>= 1) {
            s1 += __shfl_down(s1, off);
            s2 += __shfl_down(s2, off);
        }
        if (lane == 0) { red[0][wave] = s1; red[1][wave] = s2; }
        __syncthreads();
        float sum = red[0][0] + red[0][1] + red[0][2] + red[0][3];
        float sq  = red[1][0] + red[1][1] + red[1][2] + red[1][3];
        float mu  = sum * (1.f / 256.f);
        float var = sq * (1.f / 256.f) - mu * mu;
        float rs  = rsqrtf(var + 1e-3f);
        float an  = (av - mu) * rs * gam + bet;
        hs[r][tid] = bfs2f(ub[row * D2 + tid]) * an;
        __syncthreads();
    }
    const int d = tid & 127, half = tid >> 7;
    float acc[8] = {0.f, 0.f, 0.f, 0.f, 0.f, 0.f, 0.f, 0.f};
    for (int j8 = 0; j8 < 16; ++j8) {
        bf16x8 wv = *(const bf16x8*)(wft + d * D2 + half * 128 + j8 * 8);
        float wf_[8];
        #pragma unroll
        for (int j = 0; j < 8; ++j) wf_[j] = bfs2f(wv[j]);
        #pragma unroll
        for (int r = 0; r < 8; ++r) {
            const float* hp = &hs[r][half * 128 + j8 * 8];
            f32x4 h0 = *(const f32x4*)(hp);
            f32x4 h1 = *(const f32x4*)(hp + 4);
            acc[r] += h0[0]*wf_[0] + h0[1]*wf_[1] + h0[2]*wf_[2] + h0[3]*wf_[3]
                    + h1[0]*wf_[4] + h1[1]*wf_[5] + h1[2]*wf_[6] + h1[3]*wf_[7];
        }
    }
    #pragma unroll
    for (int r = 0; r < 8; ++r) part[half][r][d] = acc[r];
    __syncthreads();
    if (half == 0) {
        float bfv = bfb[d];
        #pragma unroll
        for (int r = 0; r < 8; ++r) {
            int row = row0 + r;
            float o = part[0][r][d] + part[1][r][d] + bfv;
            o = fmaxf(o, 0.f);
            o += x[row * D + d];
            out[row * D + d] = o;
        }
    }
}

// ---------------------------------------------------------------------------
extern "C" void kernel_launch(void* const* d_in, const int* in_sizes, int n_in,
                              void* d_out, int out_size, void* d_ws, size_t ws_size,
                              hipStream_t stream)
{
    const float* x     = (const float*)d_in[0];
    const float* Wq    = (const float*)d_in[1];
    const float* bq    = (const float*)d_in[2];
    const float* Wk    = (const float*)d_in[3];
    const float* bk    = (const float*)d_in[4];
    const float* Wv    = (const float*)d_in[5];
    const float* bv    = (const float*)d_in[6];
    const float* Wu    = (const float*)d_in[7];
    const float* bu    = (const float*)d_in[8];
    const float* pos_w = (const float*)d_in[9];
    const float* gamma = (const float*)d_in[10];
    const float* beta  = (const float*)d_in[11];
    const float* Wf    = (const float*)d_in[12];
    const float* bfb   = (const float*)d_in[13];
    float* out = (float*)d_out;

    // workspace (~26.1 MB; 28 MB proven safe):
    char* p = (char*)d_ws;
    short* qb      = (short*)p;  p += (size_t)BSD * 2;        // 2 MB bf16 q
    short* kb      = (short*)p;  p += (size_t)BSD * 2;        // 2 MB bf16 k
    short* vtb     = (short*)p;  p += (size_t)BSD * 2;        // 2 MB bf16 v^T [B][D][S]
    short* ubuf    = (short*)p;  p += (size_t)2 * BSD * 2;    // 4 MB bf16 u
    float* as_part = (float*)p;  p += (size_t)2 * BSD * 4;    // 8 MB fp32 self partials x2
    float* ap      = (float*)p;  p += (size_t)2 * BSD * 4;    // 8 MB fp32 pos partials x2
    short* wft     = (short*)p;  p += (size_t)D * D2 * 2;     // 64 KB bf16 Wf^T

    k_wft  <<<dim3(128),          256, 0, stream>>>(Wf, wft);
    k_qkvu <<<dim3(128, 10),      256, 0, stream>>>(x, Wq, bq, Wk, bk, Wv, bv, Wu, bu, qb, kb, vtb, ubuf);
    k_pos  <<<dim3(64, B, 2),     256, 0, stream>>>(pos_w, vtb, ap);
    k_attn <<<dim3(32, H, B * 2), 256, 0, stream>>>(qb, kb, vtb, as_part);
    k_final<<<dim3(1024),         256, 0, stream>>>(as_part, ap, ubuf, wft, gamma, beta, bfb, x, out);
}

// Round 6
// 156.172 us; speedup vs baseline: 3.9260x; 1.1702x over previous
//
#include <hip/hip_runtime.h>
#include <hip/hip_bf16.h>

#define B 4
#define S 2048
#define D 128
#define H 4
#define HD 32
#define D2 256
#define BSD (B*S*D)   // 1048576

#define LDK 40    // k LDS row stride (bf16 units), 80B
#define LDV 72    // v^T LDS row stride (bf16 units), 144B
#define LDSC 72   // sc LDS row stride (bf16 units), 144B
#define LDX 136   // xs LDS row stride (bf16 units), 272B

typedef __attribute__((ext_vector_type(8))) short bf16x8;
typedef __attribute__((ext_vector_type(4))) short bf16x4;
typedef __attribute__((ext_vector_type(4))) float f32x4;

__device__ __forceinline__ float silu_f(float z){ return z / (1.f + __expf(-z)); }
__device__ __forceinline__ short f2bfs(float f){
    __hip_bfloat16 h = __float2bfloat16(f);
    return *reinterpret_cast<short*>(&h);
}
__device__ __forceinline__ float bfs2f(short s){
    __hip_bfloat16 h = *reinterpret_cast<__hip_bfloat16*>(&s);
    return __bfloat162float(h);
}

// ---------------------------------------------------------------------------
// Kernel 0: transpose all weights to bf16 W^T[n][k]. 448 blocks x 256 = 114688.
// ---------------------------------------------------------------------------
__global__ __launch_bounds__(256) void k_wt(
    const float* __restrict__ Wq, const float* __restrict__ Wk,
    const float* __restrict__ Wv, const float* __restrict__ Wu,
    const float* __restrict__ Wf,
    short* __restrict__ wqt, short* __restrict__ wkt, short* __restrict__ wvt,
    short* __restrict__ wut, short* __restrict__ wft)
{
    int e = blockIdx.x * 256 + threadIdx.x;
    if (e < 16384) { int n = e >> 7, k = e & 127; wqt[e] = f2bfs(Wq[k * D  + n]); return; }
    e -= 16384;
    if (e < 16384) { int n = e >> 7, k = e & 127; wkt[e] = f2bfs(Wk[k * D  + n]); return; }
    e -= 16384;
    if (e < 16384) { int n = e >> 7, k = e & 127; wvt[e] = f2bfs(Wv[k * D  + n]); return; }
    e -= 16384;
    if (e < 32768) { int n = e >> 7, k = e & 127; wut[e] = f2bfs(Wu[k * D2 + n]); return; }
    e -= 32768;
    { int n = e >> 8, k = e & 255; wft[e] = f2bfs(Wf[k * D + n]); }
}

// ---------------------------------------------------------------------------
// Kernel 1 (MFMA): projections. Block = 64 rows x 64-col segment.
// W^T frags read straight from global (pre-transposed bf16, L1/L2 cached).
// blockIdx.y (cs): 0-1=q, 2-3=k, 4-5=v(transposed out), 6-9=u(bf16 out).
// ---------------------------------------------------------------------------
__global__ __launch_bounds__(256) void k_qkvu(
    const float* __restrict__ x,
    const short* __restrict__ wqt, const short* __restrict__ wkt,
    const short* __restrict__ wvt, const short* __restrict__ wut,
    const float* __restrict__ bq, const float* __restrict__ bk,
    const float* __restrict__ bv, const float* __restrict__ bu,
    short* __restrict__ qb, short* __restrict__ kb, short* __restrict__ vtb,
    short* __restrict__ ub)
{
    __shared__ short xs[64 * LDX] __attribute__((aligned(16)));
    const int rt = blockIdx.x;
    const int cs = blockIdx.y;
    const int row0 = rt * 64;
    const int tid  = threadIdx.x;
    const int w    = tid >> 6;
    const int lane = tid & 63;
    const int q16  = lane >> 4;
    const int l15  = lane & 15;

    const short* WT; const float* bias; int cn0; int kind;
    if (cs < 2)      { WT = wqt; bias = bq; cn0 = cs * 64;       kind = 0; }
    else if (cs < 4) { WT = wkt; bias = bk; cn0 = (cs - 2) * 64; kind = 1; }
    else if (cs < 6) { WT = wvt; bias = bv; cn0 = (cs - 4) * 64; kind = 2; }
    else             { WT = wut; bias = bu; cn0 = (cs - 6) * 64; kind = 3; }

    // stage X[64][128] fp32 -> bf16 LDS (vectorized, conflict-free)
    #pragma unroll
    for (int i = 0; i < 8; ++i) {
        int e = tid + i * 256;               // 0..2047
        int row = e >> 5, c4 = (e & 31) * 4;
        f32x4 xv = *(const f32x4*)(x + (row0 + row) * D + c4);
        short tmp[4];
        #pragma unroll
        for (int j = 0; j < 4; ++j) tmp[j] = f2bfs(xv[j]);
        *(bf16x4*)(xs + row * LDX + c4) = *(bf16x4*)tmp;
    }
    __syncthreads();

    f32x4 acc[4];
    #pragma unroll
    for (int ct = 0; ct < 4; ++ct) acc[ct] = (f32x4){0.f, 0.f, 0.f, 0.f};
    #pragma unroll
    for (int ks = 0; ks < 4; ++ks) {
        bf16x8 af = *(const bf16x8*)(xs + (w * 16 + l15) * LDX + ks * 32 + q16 * 8);
        #pragma unroll
        for (int ct = 0; ct < 4; ++ct) {
            bf16x8 bfr = *(const bf16x8*)(WT + (cn0 + ct * 16 + l15) * D + ks * 32 + q16 * 8);
            acc[ct] = __builtin_amdgcn_mfma_f32_16x16x32_bf16(af, bfr, acc[ct], 0, 0, 0);
        }
    }

    const int bb   = row0 / S;
    const int mloc = (row0 % S) + w * 16 + q16 * 4;
    #pragma unroll
    for (int ct = 0; ct < 4; ++ct) {
        const int c  = ct * 16 + l15;
        const float bcol = bias[cn0 + c];
        if (kind == 2) {
            short tmp[4];
            #pragma unroll
            for (int r = 0; r < 4; ++r) tmp[r] = f2bfs(silu_f(acc[ct][r] + bcol));
            *(bf16x4*)(vtb + (bb * D + cn0 + c) * S + mloc) = *(bf16x4*)tmp;
        } else if (kind == 3) {
            #pragma unroll
            for (int r = 0; r < 4; ++r)
                ub[(row0 + w * 16 + q16 * 4 + r) * D2 + cn0 + c] = f2bfs(acc[ct][r] + bcol);
        } else {
            short* dst = (kind == 0) ? qb : kb;
            #pragma unroll
            for (int r = 0; r < 4; ++r)
                dst[(row0 + w * 16 + q16 * 4 + r) * D + cn0 + c] = f2bfs(silu_f(acc[ct][r] + bcol));
        }
    }
}

// ---------------------------------------------------------------------------
// Kernel 2 (fused, MFMA): attention + pos-attn in one dispatch.
// bid < 1024: attention block (nt heavy-first, h, b, zz m-half) -> as_part.
// bid >= 1024: pos block (32-row n-tile, b, z m-half) -> ap.
// All 1536 blocks co-resident (20.5 KB LDS -> 7 blocks/CU).
// ---------------------------------------------------------------------------
__global__ __launch_bounds__(256) void k_mix(
    const short* __restrict__ qb, const short* __restrict__ kb,
    const short* __restrict__ vtb, const float* __restrict__ pos_w,
    float* __restrict__ as_part, float* __restrict__ ap)
{
    __shared__ char smem[20544] __attribute__((aligned(16)));
    const int tid  = threadIdx.x;
    const int w    = tid >> 6;
    const int lane = tid & 63;
    const int q16  = lane >> 4;
    const int l15  = lane & 15;
    const int bid  = blockIdx.x;

    if (bid < 1024) {
        // ---------------- attention role ----------------
        short* ks  = (short*)smem;                              // 64*LDK = 5120 B
        short* vt  = (short*)(smem + 5120);                     // 32*LDV = 4608 B
        short* scw = (short*)(smem + 9728) + w * 16 * LDSC;     // wave-private 16*72 bf16
        const int att = bid;
        const int nt  = 31 - (att >> 5);                        // heavy first
        const int sub = att & 31;
        const int h   = sub & 3;
        const int b   = (sub >> 2) & 3;
        const int zz  = sub >> 4;
        const int n0  = nt * 64;

        bf16x8 qfrag = *(const bf16x8*)(qb + (b * S + n0 + w * 16 + l15) * D + h * HD + q16 * 8);
        f32x4 o0 = {0.f, 0.f, 0.f, 0.f};
        f32x4 o1 = {0.f, 0.f, 0.f, 0.f};

        const int nm    = nt + 1;
        const int half1 = (nm + 1) >> 1;
        const int it_lo = zz ? half1 : 0;
        const int it_hi = zz ? nm : half1;

        for (int it = it_lo; it < it_hi; ++it) {
            const int m0 = it * 64;
            __syncthreads();
            {
                int row = tid >> 2, c8 = tid & 3;
                *(bf16x8*)(ks + row * LDK + c8 * 8) =
                    *(const bf16x8*)(kb + (b * S + m0 + row) * D + h * HD + c8 * 8);
                int d = tid >> 3, m8 = tid & 7;
                *(bf16x8*)(vt + d * LDV + m8 * 8) =
                    *(const bf16x8*)(vtb + (b * D + h * HD + d) * S + m0 + m8 * 8);
            }
            __syncthreads();
            const int n_gb = n0 + w * 16 + q16 * 4;
            #pragma unroll
            for (int t = 0; t < 4; ++t) {
                bf16x8 kf = *(const bf16x8*)(ks + (t * 16 + l15) * LDK + q16 * 8);
                f32x4 sacc = {0.f, 0.f, 0.f, 0.f};
                sacc = __builtin_amdgcn_mfma_f32_16x16x32_bf16(qfrag, kf, sacc, 0, 0, 0);
                const int m_g = m0 + t * 16 + l15;
                #pragma unroll
                for (int r = 0; r < 4; ++r) {
                    float sv = sacc[r] * 0.17677669529663687f;   // 1/sqrt(32)
                    float x2 = sv * sv;
                    float wgt = silu_f(x2);
                    if (m_g > n_gb + r) wgt = 0.f;
                    scw[(q16 * 4 + r) * LDSC + t * 16 + l15] = f2bfs(wgt);
                }
            }
            #pragma unroll
            for (int kt = 0; kt < 2; ++kt) {
                bf16x8 pf = *(const bf16x8*)(scw + l15 * LDSC + kt * 32 + q16 * 8);
                bf16x8 v0 = *(const bf16x8*)(vt + l15 * LDV        + kt * 32 + q16 * 8);
                bf16x8 v1 = *(const bf16x8*)(vt + (16 + l15) * LDV + kt * 32 + q16 * 8);
                o0 = __builtin_amdgcn_mfma_f32_16x16x32_bf16(pf, v0, o0, 0, 0, 0);
                o1 = __builtin_amdgcn_mfma_f32_16x16x32_bf16(pf, v1, o1, 0, 0, 0);
            }
        }
        float* dst = as_part + zz * BSD;
        const int nrow = n0 + w * 16 + q16 * 4;
        #pragma unroll
        for (int r = 0; r < 4; ++r) {
            dst[(b * S + nrow + r) * D + h * HD + l15]      = o0[r];
            dst[(b * S + nrow + r) * D + h * HD + 16 + l15] = o1[r];
        }
    } else {
        // ---------------- pos role ----------------
        short* pw = (short*)smem;                 // 1056 bf16 = 2112 B
        short* vt = (short*)(smem + 2112);        // 128*LDV = 18432 B
        const int pid = bid - 1024;
        const int n0  = (pid >> 3) * 32;
        const int sub = pid & 7;
        const int b   = sub >> 1;
        const int z   = sub & 1;
        const int s   = w >> 1;
        const int dh  = w & 1;

        const int base_g = 2016 + z * 1024 - n0;
        for (int i = tid; i < 1055; i += 256) pw[i] = f2bfs(pos_w[base_g + i]);

        f32x4 acc[4];
        #pragma unroll
        for (int dt = 0; dt < 4; ++dt) acc[dt] = (f32x4){0.f, 0.f, 0.f, 0.f};

        for (int mt = 0; mt < 16; ++mt) {
            __syncthreads();
            #pragma unroll
            for (int i = 0; i < 4; ++i) {
                int e = tid + i * 256;
                int d = e >> 3, m8 = e & 7;
                *(bf16x8*)(vt + d * LDV + m8 * 8) =
                    *(const bf16x8*)(vtb + (b * D + d) * S + z * 1024 + mt * 64 + m8 * 8);
            }
            __syncthreads();
            #pragma unroll
            for (int kt = 0; kt < 2; ++kt) {
                bf16x8 af;
                int idx0 = mt * 64 + kt * 32 + q16 * 8 + 31 - s * 16 - l15;
                #pragma unroll
                for (int j = 0; j < 8; ++j) af[j] = pw[idx0 + j];
                #pragma unroll
                for (int dt = 0; dt < 4; ++dt) {
                    bf16x8 bv = *(const bf16x8*)(vt + (dh * 64 + dt * 16 + l15) * LDV + kt * 32 + q16 * 8);
                    acc[dt] = __builtin_amdgcn_mfma_f32_16x16x32_bf16(af, bv, acc[dt], 0, 0, 0);
                }
            }
        }
        float* dst = ap + z * BSD;
        const int nrow = n0 + s * 16 + q16 * 4;
        #pragma unroll
        for (int dt = 0; dt < 4; ++dt)
            #pragma unroll
            for (int r = 0; r < 4; ++r)
                dst[(b * S + nrow + r) * D + dh * 64 + dt * 16 + l15] = acc[dt][r];
    }
}

// ---------------------------------------------------------------------------
// Kernel 3: a = concat(self0+self1, pos0+pos1); LayerNorm; h = u*a;
// out = relu(h@Wf + bf) + x. 8 rows/block, 3 barriers total.
// ---------------------------------------------------------------------------
__global__ __launch_bounds__(256) void k_final(
    const float* __restrict__ as_part, const float* __restrict__ ap,
    const short* __restrict__ ub, const short* __restrict__ wft,
    const float* __restrict__ gamma, const float* __restrict__ beta,
    const float* __restrict__ bfb,
    const float* __restrict__ x, float* __restrict__ out)
{
    __shared__ float hs[8][264];
    __shared__ float red[8][4][2];
    __shared__ float part[2][8][D];
    const int tid  = threadIdx.x;
    const int row0 = blockIdx.x * 8;
    const int wave = tid >> 6, lane = tid & 63;
    const float gam = gamma[tid];
    const float bet = beta[tid];

    float av[8];
    #pragma unroll
    for (int r = 0; r < 8; ++r) {
        const int row = row0 + r;
        float v_;
        if (tid < 128) v_ = as_part[row * D + tid] + as_part[BSD + row * D + tid];
        else           v_ = ap[row * D + (tid - 128)] + ap[BSD + row * D + (tid - 128)];
        av[r] = v_;
        float s1 = v_, s2 = v_ * v_;
        #pragma unroll
        for (int off = 32; off > 0; off >>= 1) {
            s1 += __shfl_down(s1, off);
            s2 += __shfl_down(s2, off);
        }
        if (lane == 0) { red[r][wave][0] = s1; red[r][wave][1] = s2; }
    }
    __syncthreads();
    #pragma unroll
    for (int r = 0; r < 8; ++r) {
        float sum = red[r][0][0] + red[r][1][0] + red[r][2][0] + red[r][3][0];
        float sq  = red[r][0][1] + red[r][1][1] + red[r][2][1] + red[r][3][1];
        float mu  = sum * (1.f / 256.f);
        float var = sq * (1.f / 256.f) - mu * mu;
        float rs  = rsqrtf(var + 1e-3f);
        float an  = (av[r] - mu) * rs * gam + bet;
        hs[r][tid] = bfs2f(ub[(row0 + r) * D2 + tid]) * an;
    }
    __syncthreads();

    const int d = tid & 127, half = tid >> 7;
    float acc[8] = {0.f, 0.f, 0.f, 0.f, 0.f, 0.f, 0.f, 0.f};
    for (int j8 = 0; j8 < 16; ++j8) {
        bf16x8 wv = *(const bf16x8*)(wft + d * D2 + half * 128 + j8 * 8);
        float wf_[8];
        #pragma unroll
        for (int j = 0; j < 8; ++j) wf_[j] = bfs2f(wv[j]);
        #pragma unroll
        for (int r = 0; r < 8; ++r) {
            const float* hp = &hs[r][half * 128 + j8 * 8];
            f32x4 h0 = *(const f32x4*)(hp);
            f32x4 h1 = *(const f32x4*)(hp + 4);
            acc[r] += h0[0]*wf_[0] + h0[1]*wf_[1] + h0[2]*wf_[2] + h0[3]*wf_[3]
                    + h1[0]*wf_[4] + h1[1]*wf_[5] + h1[2]*wf_[6] + h1[3]*wf_[7];
        }
    }
    #pragma unroll
    for (int r = 0; r < 8; ++r) part[half][r][d] = acc[r];
    __syncthreads();
    if (half == 0) {
        float bfv = bfb[d];
        #pragma unroll
        for (int r = 0; r < 8; ++r) {
            int row = row0 + r;
            float o = part[0][r][d] + part[1][r][d] + bfv;
            o = fmaxf(o, 0.f);
            o += x[row * D + d];
            out[row * D + d] = o;
        }
    }
}

// ---------------------------------------------------------------------------
extern "C" void kernel_launch(void* const* d_in, const int* in_sizes, int n_in,
                              void* d_out, int out_size, void* d_ws, size_t ws_size,
                              hipStream_t stream)
{
    const float* x     = (const float*)d_in[0];
    const float* Wq    = (const float*)d_in[1];
    const float* bq    = (const float*)d_in[2];
    const float* Wk    = (const float*)d_in[3];
    const float* bk    = (const float*)d_in[4];
    const float* Wv    = (const float*)d_in[5];
    const float* bv    = (const float*)d_in[6];
    const float* Wu    = (const float*)d_in[7];
    const float* bu    = (const float*)d_in[8];
    const float* pos_w = (const float*)d_in[9];
    const float* gamma = (const float*)d_in[10];
    const float* beta  = (const float*)d_in[11];
    const float* Wf    = (const float*)d_in[12];
    const float* bfb   = (const float*)d_in[13];
    float* out = (float*)d_out;

    // workspace (~26.2 MB; 28 MB proven safe):
    char* p = (char*)d_ws;
    short* qb      = (short*)p;  p += (size_t)BSD * 2;        // 2 MB bf16 q
    short* kb      = (short*)p;  p += (size_t)BSD * 2;        // 2 MB bf16 k
    short* vtb     = (short*)p;  p += (size_t)BSD * 2;        // 2 MB bf16 v^T [B][D][S]
    short* ubuf    = (short*)p;  p += (size_t)2 * BSD * 2;    // 4 MB bf16 u
    float* as_part = (float*)p;  p += (size_t)2 * BSD * 4;    // 8 MB fp32 self partials x2
    float* ap      = (float*)p;  p += (size_t)2 * BSD * 4;    // 8 MB fp32 pos partials x2
    short* wqt     = (short*)p;  p += (size_t)D * D * 2;      // 32 KB bf16 Wq^T
    short* wkt     = (short*)p;  p += (size_t)D * D * 2;      // 32 KB bf16 Wk^T
    short* wvt     = (short*)p;  p += (size_t)D * D * 2;      // 32 KB bf16 Wv^T
    short* wut     = (short*)p;  p += (size_t)D2 * D * 2;     // 64 KB bf16 Wu^T
    short* wft     = (short*)p;  p += (size_t)D * D2 * 2;     // 64 KB bf16 Wf^T

    k_wt   <<<dim3(448),     256, 0, stream>>>(Wq, Wk, Wv, Wu, Wf, wqt, wkt, wvt, wut, wft);
    k_qkvu <<<dim3(128, 10), 256, 0, stream>>>(x, wqt, wkt, wvt, wut, bq, bk, bv, bu, qb, kb, vtb, ubuf);
    k_mix  <<<dim3(1536),    256, 0, stream>>>(qb, kb, vtb, pos_w, as_part, ap);
    k_final<<<dim3(1024),    256, 0, stream>>>(as_part, ap, ubuf, wft, gamma, beta, bfb, x, out);
}

// Round 7
// 143.370 us; speedup vs baseline: 4.2766x; 1.0893x over previous
//
#include <hip/hip_runtime.h>
#include <hip/hip_bf16.h>

#define B 4
#define S 2048
#define D 128
#define H 4
#define HD 32
#define D2 256
#define BSD (B*S*D)   // 1048576

#define LDK 40    // k LDS row stride (bf16 units), 80B
#define LDV 72    // v^T LDS row stride (bf16 units), 144B
#define LDSC 72   // sc LDS row stride (bf16 units), 144B
#define LDX 136   // xs LDS row stride (bf16 units): 68 dw = 4 mod 32 -> 2-way free
#define LDH 264   // hsb LDS row stride (bf16 units): 132 dw = 4 mod 32 -> 2-way free

typedef __attribute__((ext_vector_type(8))) short bf16x8;
typedef __attribute__((ext_vector_type(4))) short bf16x4;
typedef __attribute__((ext_vector_type(4))) float f32x4;

__device__ __forceinline__ float silu_f(float z){ return z / (1.f + __expf(-z)); }
__device__ __forceinline__ short f2bfs(float f){
    __hip_bfloat16 h = __float2bfloat16(f);
    return *reinterpret_cast<short*>(&h);
}
__device__ __forceinline__ float bfs2f(short s){
    __hip_bfloat16 h = *reinterpret_cast<__hip_bfloat16*>(&s);
    return __bfloat162float(h);
}

// ---------------------------------------------------------------------------
// Kernel 0: transpose all weights to bf16 W^T[n][k]. 448 blocks x 256.
// ---------------------------------------------------------------------------
__global__ __launch_bounds__(256) void k_wt(
    const float* __restrict__ Wq, const float* __restrict__ Wk,
    const float* __restrict__ Wv, const float* __restrict__ Wu,
    const float* __restrict__ Wf,
    short* __restrict__ wqt, short* __restrict__ wkt, short* __restrict__ wvt,
    short* __restrict__ wut, short* __restrict__ wft)
{
    int e = blockIdx.x * 256 + threadIdx.x;
    if (e < 16384) { int n = e >> 7, k = e & 127; wqt[e] = f2bfs(Wq[k * D  + n]); return; }
    e -= 16384;
    if (e < 16384) { int n = e >> 7, k = e & 127; wkt[e] = f2bfs(Wk[k * D  + n]); return; }
    e -= 16384;
    if (e < 16384) { int n = e >> 7, k = e & 127; wvt[e] = f2bfs(Wv[k * D  + n]); return; }
    e -= 16384;
    if (e < 32768) { int n = e >> 7, k = e & 127; wut[e] = f2bfs(Wu[k * D2 + n]); return; }
    e -= 32768;
    { int n = e >> 8, k = e & 255; wft[e] = f2bfs(Wf[k * D + n]); }
}

// ---------------------------------------------------------------------------
// Kernel 1 (MFMA): projections. 512 blocks x 16 rows; block covers all 640
// out cols (x staged ONCE). Wave w handles out-col range [w*160, w*160+160).
// ---------------------------------------------------------------------------
__global__ __launch_bounds__(256) void k_qkvu(
    const float* __restrict__ x,
    const short* __restrict__ wqt, const short* __restrict__ wkt,
    const short* __restrict__ wvt, const short* __restrict__ wut,
    const float* __restrict__ bq, const float* __restrict__ bk,
    const float* __restrict__ bv, const float* __restrict__ bu,
    short* __restrict__ qb, short* __restrict__ kb, short* __restrict__ vtb,
    short* __restrict__ ub)
{
    __shared__ short xs[16 * LDX] __attribute__((aligned(16)));
    const int row0 = blockIdx.x * 16;
    const int tid  = threadIdx.x;
    const int w    = tid >> 6;
    const int lane = tid & 63;
    const int q16  = lane >> 4;
    const int l15  = lane & 15;

    // stage X[16][128] fp32 -> bf16 LDS once
    #pragma unroll
    for (int i = 0; i < 2; ++i) {
        int quad = tid + i * 256;            // 0..511
        int row = quad >> 5, c4 = (quad & 31) * 4;
        f32x4 xv = *(const f32x4*)(x + (row0 + row) * D + c4);
        short tmp[4];
        #pragma unroll
        for (int j = 0; j < 4; ++j) tmp[j] = f2bfs(xv[j]);
        *(bf16x4*)(xs + row * LDX + c4) = *(bf16x4*)tmp;
    }
    __syncthreads();

    // A-frags once per wave (rows = l15, reused for all 10 col-tiles)
    bf16x8 af[4];
    #pragma unroll
    for (int ks = 0; ks < 4; ++ks)
        af[ks] = *(const bf16x8*)(xs + l15 * LDX + ks * 32 + q16 * 8);

    const int bb   = row0 / S;
    const int mloc = (row0 % S) + q16 * 4;

    #pragma unroll
    for (int t = 0; t < 10; ++t) {
        const int g = w * 160 + t * 16;      // global out-col tile start
        const short* WT; const float* bias; int base; int kind;
        if (g < 128)      { WT = wqt; bias = bq; base = 0;   kind = 0; }
        else if (g < 256) { WT = wkt; bias = bk; base = 128; kind = 1; }
        else if (g < 384) { WT = wvt; bias = bv; base = 256; kind = 2; }
        else              { WT = wut; bias = bu; base = 384; kind = 3; }
        const int nloc = g - base;
        f32x4 acc = {0.f, 0.f, 0.f, 0.f};
        #pragma unroll
        for (int ks = 0; ks < 4; ++ks) {
            bf16x8 bfr = *(const bf16x8*)(WT + (nloc + l15) * D + ks * 32 + q16 * 8);
            acc = __builtin_amdgcn_mfma_f32_16x16x32_bf16(af[ks], bfr, acc, 0, 0, 0);
        }
        const float bcol = bias[nloc + l15];
        if (kind == 2) {
            short tmp[4];
            #pragma unroll
            for (int r = 0; r < 4; ++r) tmp[r] = f2bfs(silu_f(acc[r] + bcol));
            *(bf16x4*)(vtb + (bb * D + nloc + l15) * S + mloc) = *(bf16x4*)tmp;
        } else if (kind == 3) {
            #pragma unroll
            for (int r = 0; r < 4; ++r)
                ub[(row0 + q16 * 4 + r) * D2 + nloc + l15] = f2bfs(acc[r] + bcol);
        } else {
            short* dst = (kind == 0) ? qb : kb;
            #pragma unroll
            for (int r = 0; r < 4; ++r)
                dst[(row0 + q16 * 4 + r) * D + nloc + l15] = f2bfs(silu_f(acc[r] + bcol));
        }
    }
}

// ---------------------------------------------------------------------------
// Kernel 2 (fused, MFMA): attention + pos-attn in one dispatch. (unchanged)
// ---------------------------------------------------------------------------
__global__ __launch_bounds__(256) void k_mix(
    const short* __restrict__ qb, const short* __restrict__ kb,
    const short* __restrict__ vtb, const float* __restrict__ pos_w,
    float* __restrict__ as_part, float* __restrict__ ap)
{
    __shared__ char smem[20544] __attribute__((aligned(16)));
    const int tid  = threadIdx.x;
    const int w    = tid >> 6;
    const int lane = tid & 63;
    const int q16  = lane >> 4;
    const int l15  = lane & 15;
    const int bid  = blockIdx.x;

    if (bid < 1024) {
        short* ks  = (short*)smem;
        short* vt  = (short*)(smem + 5120);
        short* scw = (short*)(smem + 9728) + w * 16 * LDSC;
        const int att = bid;
        const int nt  = 31 - (att >> 5);
        const int sub = att & 31;
        const int h   = sub & 3;
        const int b   = (sub >> 2) & 3;
        const int zz  = sub >> 4;
        const int n0  = nt * 64;

        bf16x8 qfrag = *(const bf16x8*)(qb + (b * S + n0 + w * 16 + l15) * D + h * HD + q16 * 8);
        f32x4 o0 = {0.f, 0.f, 0.f, 0.f};
        f32x4 o1 = {0.f, 0.f, 0.f, 0.f};

        const int nm    = nt + 1;
        const int half1 = (nm + 1) >> 1;
        const int it_lo = zz ? half1 : 0;
        const int it_hi = zz ? nm : half1;

        for (int it = it_lo; it < it_hi; ++it) {
            const int m0 = it * 64;
            __syncthreads();
            {
                int row = tid >> 2, c8 = tid & 3;
                *(bf16x8*)(ks + row * LDK + c8 * 8) =
                    *(const bf16x8*)(kb + (b * S + m0 + row) * D + h * HD + c8 * 8);
                int d = tid >> 3, m8 = tid & 7;
                *(bf16x8*)(vt + d * LDV + m8 * 8) =
                    *(const bf16x8*)(vtb + (b * D + h * HD + d) * S + m0 + m8 * 8);
            }
            __syncthreads();
            const int n_gb = n0 + w * 16 + q16 * 4;
            #pragma unroll
            for (int t = 0; t < 4; ++t) {
                bf16x8 kf = *(const bf16x8*)(ks + (t * 16 + l15) * LDK + q16 * 8);
                f32x4 sacc = {0.f, 0.f, 0.f, 0.f};
                sacc = __builtin_amdgcn_mfma_f32_16x16x32_bf16(qfrag, kf, sacc, 0, 0, 0);
                const int m_g = m0 + t * 16 + l15;
                #pragma unroll
                for (int r = 0; r < 4; ++r) {
                    float sv = sacc[r] * 0.17677669529663687f;   // 1/sqrt(32)
                    float x2 = sv * sv;
                    float wgt = silu_f(x2);
                    if (m_g > n_gb + r) wgt = 0.f;
                    scw[(q16 * 4 + r) * LDSC + t * 16 + l15] = f2bfs(wgt);
                }
            }
            #pragma unroll
            for (int kt = 0; kt < 2; ++kt) {
                bf16x8 pf = *(const bf16x8*)(scw + l15 * LDSC + kt * 32 + q16 * 8);
                bf16x8 v0 = *(const bf16x8*)(vt + l15 * LDV        + kt * 32 + q16 * 8);
                bf16x8 v1 = *(const bf16x8*)(vt + (16 + l15) * LDV + kt * 32 + q16 * 8);
                o0 = __builtin_amdgcn_mfma_f32_16x16x32_bf16(pf, v0, o0, 0, 0, 0);
                o1 = __builtin_amdgcn_mfma_f32_16x16x32_bf16(pf, v1, o1, 0, 0, 0);
            }
        }
        float* dst = as_part + zz * BSD;
        const int nrow = n0 + w * 16 + q16 * 4;
        #pragma unroll
        for (int r = 0; r < 4; ++r) {
            dst[(b * S + nrow + r) * D + h * HD + l15]      = o0[r];
            dst[(b * S + nrow + r) * D + h * HD + 16 + l15] = o1[r];
        }
    } else {
        short* pw = (short*)smem;
        short* vt = (short*)(smem + 2112);
        const int pid = bid - 1024;
        const int n0  = (pid >> 3) * 32;
        const int sub = pid & 7;
        const int b   = sub >> 1;
        const int z   = sub & 1;
        const int s   = w >> 1;
        const int dh  = w & 1;

        const int base_g = 2016 + z * 1024 - n0;
        for (int i = tid; i < 1055; i += 256) pw[i] = f2bfs(pos_w[base_g + i]);

        f32x4 acc[4];
        #pragma unroll
        for (int dt = 0; dt < 4; ++dt) acc[dt] = (f32x4){0.f, 0.f, 0.f, 0.f};

        for (int mt = 0; mt < 16; ++mt) {
            __syncthreads();
            #pragma unroll
            for (int i = 0; i < 4; ++i) {
                int e = tid + i * 256;
                int d = e >> 3, m8 = e & 7;
                *(bf16x8*)(vt + d * LDV + m8 * 8) =
                    *(const bf16x8*)(vtb + (b * D + d) * S + z * 1024 + mt * 64 + m8 * 8);
            }
            __syncthreads();
            #pragma unroll
            for (int kt = 0; kt < 2; ++kt) {
                bf16x8 af;
                int idx0 = mt * 64 + kt * 32 + q16 * 8 + 31 - s * 16 - l15;
                #pragma unroll
                for (int j = 0; j < 8; ++j) af[j] = pw[idx0 + j];
                #pragma unroll
                for (int dt = 0; dt < 4; ++dt) {
                    bf16x8 bv = *(const bf16x8*)(vt + (dh * 64 + dt * 16 + l15) * LDV + kt * 32 + q16 * 8);
                    acc[dt] = __builtin_amdgcn_mfma_f32_16x16x32_bf16(af, bv, acc[dt], 0, 0, 0);
                }
            }
        }
        float* dst = ap + z * BSD;
        const int nrow = n0 + s * 16 + q16 * 4;
        #pragma unroll
        for (int dt = 0; dt < 4; ++dt)
            #pragma unroll
            for (int r = 0; r < 4; ++r)
                dst[(b * S + nrow + r) * D + dh * 64 + dt * 16 + l15] = acc[dt][r];
    }
}

// ---------------------------------------------------------------------------
// Kernel 3 (MFMA): sum partials -> LN -> h=u*an (bf16 LDS) -> h@Wf -> relu+x.
// 512 blocks x 16 rows.
// ---------------------------------------------------------------------------
__global__ __launch_bounds__(256) void k_final(
    const float* __restrict__ as_part, const float* __restrict__ ap,
    const short* __restrict__ ub, const short* __restrict__ wft,
    const float* __restrict__ gamma, const float* __restrict__ beta,
    const float* __restrict__ bfb,
    const float* __restrict__ x, float* __restrict__ out)
{
    __shared__ short hsb[16 * LDH] __attribute__((aligned(16)));
    const int tid  = threadIdx.x;
    const int row0 = blockIdx.x * 16;

    // ---- Phase A: LN + u-mult, 16 lanes per row ----
    {
        const int row = tid >> 4;            // 0..15
        const int c   = tid & 15;
        float av[16];
        float s1 = 0.f, s2 = 0.f;
        #pragma unroll
        for (int j = 0; j < 16; ++j) {
            int col = c + j * 16;
            float v_;
            if (col < 128) v_ = as_part[(row0 + row) * D + col] + as_part[BSD + (row0 + row) * D + col];
            else           v_ = ap[(row0 + row) * D + col - 128] + ap[BSD + (row0 + row) * D + col - 128];
            av[j] = v_;
            s1 += v_;
            s2 += v_ * v_;
        }
        #pragma unroll
        for (int off = 1; off < 16; off <<= 1) {
            s1 += __shfl_xor(s1, off);
            s2 += __shfl_xor(s2, off);
        }
        float mu  = s1 * (1.f / 256.f);
        float var = s2 * (1.f / 256.f) - mu * mu;
        float rs  = rsqrtf(var + 1e-3f);
        #pragma unroll
        for (int j = 0; j < 16; ++j) {
            int col = c + j * 16;
            float an = (av[j] - mu) * rs * gamma[col] + beta[col];
            float h  = bfs2f(ub[(row0 + row) * D2 + col]) * an;
            hsb[row * LDH + col] = f2bfs(h);
        }
    }
    __syncthreads();

    // ---- Phase B: h[16][256] @ Wf^T -> out[16][128], wave w covers 32 cols ----
    const int w    = tid >> 6;
    const int lane = tid & 63;
    const int q16  = lane >> 4;
    const int l15  = lane & 15;
    f32x4 o[2];
    o[0] = (f32x4){0.f, 0.f, 0.f, 0.f};
    o[1] = (f32x4){0.f, 0.f, 0.f, 0.f};
    #pragma unroll
    for (int ks = 0; ks < 8; ++ks) {
        bf16x8 af = *(const bf16x8*)(hsb + l15 * LDH + ks * 32 + q16 * 8);
        #pragma unroll
        for (int ci = 0; ci < 2; ++ci) {
            const int ct = w * 2 + ci;
            bf16x8 bfr = *(const bf16x8*)(wft + (ct * 16 + l15) * D2 + ks * 32 + q16 * 8);
            o[ci] = __builtin_amdgcn_mfma_f32_16x16x32_bf16(af, bfr, o[ci], 0, 0, 0);
        }
    }
    #pragma unroll
    for (int ci = 0; ci < 2; ++ci) {
        const int n = (w * 2 + ci) * 16 + l15;
        const float bfv = bfb[n];
        #pragma unroll
        for (int r = 0; r < 4; ++r) {
            const int row = row0 + q16 * 4 + r;
            float oo = o[ci][r] + bfv;
            oo = fmaxf(oo, 0.f);
            oo += x[row * D + n];
            out[row * D + n] = oo;
        }
    }
}

// ---------------------------------------------------------------------------
extern "C" void kernel_launch(void* const* d_in, const int* in_sizes, int n_in,
                              void* d_out, int out_size, void* d_ws, size_t ws_size,
                              hipStream_t stream)
{
    const float* x     = (const float*)d_in[0];
    const float* Wq    = (const float*)d_in[1];
    const float* bq    = (const float*)d_in[2];
    const float* Wk    = (const float*)d_in[3];
    const float* bk    = (const float*)d_in[4];
    const float* Wv    = (const float*)d_in[5];
    const float* bv    = (const float*)d_in[6];
    const float* Wu    = (const float*)d_in[7];
    const float* bu    = (const float*)d_in[8];
    const float* pos_w = (const float*)d_in[9];
    const float* gamma = (const float*)d_in[10];
    const float* beta  = (const float*)d_in[11];
    const float* Wf    = (const float*)d_in[12];
    const float* bfb   = (const float*)d_in[13];
    float* out = (float*)d_out;

    // workspace (~26.2 MB; 28 MB proven safe):
    char* p = (char*)d_ws;
    short* qb      = (short*)p;  p += (size_t)BSD * 2;        // 2 MB bf16 q
    short* kb      = (short*)p;  p += (size_t)BSD * 2;        // 2 MB bf16 k
    short* vtb     = (short*)p;  p += (size_t)BSD * 2;        // 2 MB bf16 v^T [B][D][S]
    short* ubuf    = (short*)p;  p += (size_t)2 * BSD * 2;    // 4 MB bf16 u
    float* as_part = (float*)p;  p += (size_t)2 * BSD * 4;    // 8 MB fp32 self partials x2
    float* ap      = (float*)p;  p += (size_t)2 * BSD * 4;    // 8 MB fp32 pos partials x2
    short* wqt     = (short*)p;  p += (size_t)D * D * 2;      // 32 KB bf16 Wq^T
    short* wkt     = (short*)p;  p += (size_t)D * D * 2;      // 32 KB bf16 Wk^T
    short* wvt     = (short*)p;  p += (size_t)D * D * 2;      // 32 KB bf16 Wv^T
    short* wut     = (short*)p;  p += (size_t)D2 * D * 2;     // 64 KB bf16 Wu^T
    short* wft     = (short*)p;  p += (size_t)D * D2 * 2;     // 64 KB bf16 Wf^T

    k_wt   <<<dim3(448),  256, 0, stream>>>(Wq, Wk, Wv, Wu, Wf, wqt, wkt, wvt, wut, wft);
    k_qkvu <<<dim3(512),  256, 0, stream>>>(x, wqt, wkt, wvt, wut, bq, bk, bv, bu, qb, kb, vtb, ubuf);
    k_mix  <<<dim3(1536), 256, 0, stream>>>(qb, kb, vtb, pos_w, as_part, ap);
    k_final<<<dim3(512),  256, 0, stream>>>(as_part, ap, ubuf, wft, gamma, beta, bfb, x, out);
}

// Round 9
// 141.622 us; speedup vs baseline: 4.3294x; 1.0123x over previous
//
#include <hip/hip_runtime.h>
#include <hip/hip_bf16.h>

#define B 4
#define S 2048
#define D 128
#define H 4
#define HD 32
#define D2 256
#define BSD (B*S*D)   // 1048576

#define LDK 40    // k LDS row stride (bf16 units), 80B
#define LDV 72    // v^T LDS row stride (bf16 units), 144B
#define LDSC 72   // sc LDS row stride (bf16 units), 144B
#define LDX 136   // xs LDS row stride (bf16 units)
#define LDH 264   // hsb LDS row stride (bf16 units)

typedef __attribute__((ext_vector_type(8))) short bf16x8;
typedef __attribute__((ext_vector_type(4))) short bf16x4;
typedef __attribute__((ext_vector_type(4))) float f32x4;

__device__ __forceinline__ float silu_f(float z){ return z / (1.f + __expf(-z)); }
__device__ __forceinline__ short f2bfs(float f){
    __hip_bfloat16 h = __float2bfloat16(f);
    return *reinterpret_cast<short*>(&h);
}
__device__ __forceinline__ float bfs2f(short s){
    __hip_bfloat16 h = *reinterpret_cast<__hip_bfloat16*>(&s);
    return __bfloat162float(h);
}

// ---------------------------------------------------------------------------
// Kernel 0: transpose all weights to bf16 W^T[n][k]. 448 blocks x 256.
// ---------------------------------------------------------------------------
__global__ __launch_bounds__(256) void k_wt(
    const float* __restrict__ Wq, const float* __restrict__ Wk,
    const float* __restrict__ Wv, const float* __restrict__ Wu,
    const float* __restrict__ Wf,
    short* __restrict__ wqt, short* __restrict__ wkt, short* __restrict__ wvt,
    short* __restrict__ wut, short* __restrict__ wft)
{
    int e = blockIdx.x * 256 + threadIdx.x;
    if (e < 16384) { int n = e >> 7, k = e & 127; wqt[e] = f2bfs(Wq[k * D  + n]); return; }
    e -= 16384;
    if (e < 16384) { int n = e >> 7, k = e & 127; wkt[e] = f2bfs(Wk[k * D  + n]); return; }
    e -= 16384;
    if (e < 16384) { int n = e >> 7, k = e & 127; wvt[e] = f2bfs(Wv[k * D  + n]); return; }
    e -= 16384;
    if (e < 32768) { int n = e >> 7, k = e & 127; wut[e] = f2bfs(Wu[k * D2 + n]); return; }
    e -= 32768;
    { int n = e >> 8, k = e & 255; wft[e] = f2bfs(Wf[k * D + n]); }
}

// ---------------------------------------------------------------------------
// Kernel 1 (MFMA): projections. Grid (512, 2): 16 rows x 320-col half.
// Wave w covers cols [by*320 + w*80, +80) = 5 tiles of 16. 4 blocks/CU.
// ---------------------------------------------------------------------------
__global__ __launch_bounds__(256) void k_qkvu(
    const float* __restrict__ x,
    const short* __restrict__ wqt, const short* __restrict__ wkt,
    const short* __restrict__ wvt, const short* __restrict__ wut,
    const float* __restrict__ bq, const float* __restrict__ bk,
    const float* __restrict__ bv, const float* __restrict__ bu,
    short* __restrict__ qb, short* __restrict__ kb, short* __restrict__ vtb,
    short* __restrict__ ub)
{
    __shared__ short xs[16 * LDX] __attribute__((aligned(16)));
    const int row0 = blockIdx.x * 16;
    const int by   = blockIdx.y;
    const int tid  = threadIdx.x;
    const int w    = tid >> 6;
    const int lane = tid & 63;
    const int q16  = lane >> 4;
    const int l15  = lane & 15;

    // stage X[16][128] fp32 -> bf16 LDS once
    #pragma unroll
    for (int i = 0; i < 2; ++i) {
        int quad = tid + i * 256;            // 0..511
        int row = quad >> 5, c4 = (quad & 31) * 4;
        f32x4 xv = *(const f32x4*)(x + (row0 + row) * D + c4);
        short tmp[4];
        #pragma unroll
        for (int j = 0; j < 4; ++j) tmp[j] = f2bfs(xv[j]);
        *(bf16x4*)(xs + row * LDX + c4) = *(bf16x4*)tmp;
    }
    __syncthreads();

    bf16x8 af[4];
    #pragma unroll
    for (int ks = 0; ks < 4; ++ks)
        af[ks] = *(const bf16x8*)(xs + l15 * LDX + ks * 32 + q16 * 8);

    const int bb   = row0 / S;
    const int mloc = (row0 % S) + q16 * 4;

    #pragma unroll
    for (int t = 0; t < 5; ++t) {
        const int g = by * 320 + w * 80 + t * 16;   // global out-col tile start
        const short* WT; const float* bias; int base; int kind;
        if (g < 128)      { WT = wqt; bias = bq; base = 0;   kind = 0; }
        else if (g < 256) { WT = wkt; bias = bk; base = 128; kind = 1; }
        else if (g < 384) { WT = wvt; bias = bv; base = 256; kind = 2; }
        else              { WT = wut; bias = bu; base = 384; kind = 3; }
        const int nloc = g - base;
        f32x4 acc = {0.f, 0.f, 0.f, 0.f};
        #pragma unroll
        for (int ks = 0; ks < 4; ++ks) {
            bf16x8 bfr = *(const bf16x8*)(WT + (nloc + l15) * D + ks * 32 + q16 * 8);
            acc = __builtin_amdgcn_mfma_f32_16x16x32_bf16(af[ks], bfr, acc, 0, 0, 0);
        }
        const float bcol = bias[nloc + l15];
        if (kind == 2) {
            short tmp[4];
            #pragma unroll
            for (int r = 0; r < 4; ++r) tmp[r] = f2bfs(silu_f(acc[r] + bcol));
            *(bf16x4*)(vtb + (bb * D + nloc + l15) * S + mloc) = *(bf16x4*)tmp;
        } else if (kind == 3) {
            #pragma unroll
            for (int r = 0; r < 4; ++r)
                ub[(row0 + q16 * 4 + r) * D2 + nloc + l15] = f2bfs(acc[r] + bcol);
        } else {
            short* dst = (kind == 0) ? qb : kb;
            #pragma unroll
            for (int r = 0; r < 4; ++r)
                dst[(row0 + q16 * 4 + r) * D + nloc + l15] = f2bfs(silu_f(acc[r] + bcol));
        }
    }
}

// ---------------------------------------------------------------------------
// Kernel 2 (fused, MFMA): attention + pos-attn in one dispatch.
// Non-diagonal iterations (it != nt) carry no mask VALU; the diagonal tile
// (it == nt) is masked — correct for every (nt, zz) incl. nt=0.
// ---------------------------------------------------------------------------
__global__ __launch_bounds__(256) void k_mix(
    const short* __restrict__ qb, const short* __restrict__ kb,
    const short* __restrict__ vtb, const float* __restrict__ pos_w,
    float* __restrict__ as_part, float* __restrict__ ap)
{
    __shared__ char smem[20544] __attribute__((aligned(16)));
    const int tid  = threadIdx.x;
    const int w    = tid >> 6;
    const int lane = tid & 63;
    const int q16  = lane >> 4;
    const int l15  = lane & 15;
    const int bid  = blockIdx.x;

    if (bid < 1024) {
        short* ks  = (short*)smem;
        short* vt  = (short*)(smem + 5120);
        short* scw = (short*)(smem + 9728) + w * 16 * LDSC;
        const int att = bid;
        const int nt  = 31 - (att >> 5);
        const int sub = att & 31;
        const int h   = sub & 3;
        const int b   = (sub >> 2) & 3;
        const int zz  = sub >> 4;
        const int n0  = nt * 64;

        bf16x8 qfrag = *(const bf16x8*)(qb + (b * S + n0 + w * 16 + l15) * D + h * HD + q16 * 8);
        f32x4 o0 = {0.f, 0.f, 0.f, 0.f};
        f32x4 o1 = {0.f, 0.f, 0.f, 0.f};

        const int nm    = nt + 1;
        const int half1 = (nm + 1) >> 1;
        const int it_lo = zz ? half1 : 0;
        const int it_hi = zz ? nm : half1;

        for (int it = it_lo; it < it_hi; ++it) {
            const int m0 = it * 64;
            __syncthreads();
            {
                int row = tid >> 2, c8 = tid & 3;
                *(bf16x8*)(ks + row * LDK + c8 * 8) =
                    *(const bf16x8*)(kb + (b * S + m0 + row) * D + h * HD + c8 * 8);
                int d = tid >> 3, m8 = tid & 7;
                *(bf16x8*)(vt + d * LDV + m8 * 8) =
                    *(const bf16x8*)(vtb + (b * D + h * HD + d) * S + m0 + m8 * 8);
            }
            __syncthreads();
            if (it != nt) {
                // non-diagonal: no masking
                #pragma unroll
                for (int t = 0; t < 4; ++t) {
                    bf16x8 kf = *(const bf16x8*)(ks + (t * 16 + l15) * LDK + q16 * 8);
                    f32x4 sacc = {0.f, 0.f, 0.f, 0.f};
                    sacc = __builtin_amdgcn_mfma_f32_16x16x32_bf16(qfrag, kf, sacc, 0, 0, 0);
                    #pragma unroll
                    for (int r = 0; r < 4; ++r) {
                        float sv = sacc[r] * 0.17677669529663687f;   // 1/sqrt(32)
                        float wgt = silu_f(sv * sv);
                        scw[(q16 * 4 + r) * LDSC + t * 16 + l15] = f2bfs(wgt);
                    }
                }
            } else {
                // diagonal tile: causal mask
                const int n_gb = n0 + w * 16 + q16 * 4;
                #pragma unroll
                for (int t = 0; t < 4; ++t) {
                    bf16x8 kf = *(const bf16x8*)(ks + (t * 16 + l15) * LDK + q16 * 8);
                    f32x4 sacc = {0.f, 0.f, 0.f, 0.f};
                    sacc = __builtin_amdgcn_mfma_f32_16x16x32_bf16(qfrag, kf, sacc, 0, 0, 0);
                    const int m_g = m0 + t * 16 + l15;
                    #pragma unroll
                    for (int r = 0; r < 4; ++r) {
                        float sv = sacc[r] * 0.17677669529663687f;
                        float wgt = silu_f(sv * sv);
                        if (m_g > n_gb + r) wgt = 0.f;
                        scw[(q16 * 4 + r) * LDSC + t * 16 + l15] = f2bfs(wgt);
                    }
                }
            }
            #pragma unroll
            for (int kt = 0; kt < 2; ++kt) {
                bf16x8 pf = *(const bf16x8*)(scw + l15 * LDSC + kt * 32 + q16 * 8);
                bf16x8 v0 = *(const bf16x8*)(vt + l15 * LDV        + kt * 32 + q16 * 8);
                bf16x8 v1 = *(const bf16x8*)(vt + (16 + l15) * LDV + kt * 32 + q16 * 8);
                o0 = __builtin_amdgcn_mfma_f32_16x16x32_bf16(pf, v0, o0, 0, 0, 0);
                o1 = __builtin_amdgcn_mfma_f32_16x16x32_bf16(pf, v1, o1, 0, 0, 0);
            }
        }
        float* dst = as_part + zz * BSD;
        const int nrow = n0 + w * 16 + q16 * 4;
        #pragma unroll
        for (int r = 0; r < 4; ++r) {
            dst[(b * S + nrow + r) * D + h * HD + l15]      = o0[r];
            dst[(b * S + nrow + r) * D + h * HD + 16 + l15] = o1[r];
        }
    } else {
        short* pw = (short*)smem;
        short* vt = (short*)(smem + 2112);
        const int pid = bid - 1024;
        const int n0  = (pid >> 3) * 32;
        const int sub = pid & 7;
        const int b   = sub >> 1;
        const int z   = sub & 1;
        const int s   = w >> 1;
        const int dh  = w & 1;

        const int base_g = 2016 + z * 1024 - n0;
        for (int i = tid; i < 1055; i += 256) pw[i] = f2bfs(pos_w[base_g + i]);

        f32x4 acc[4];
        #pragma unroll
        for (int dt = 0; dt < 4; ++dt) acc[dt] = (f32x4){0.f, 0.f, 0.f, 0.f};

        for (int mt = 0; mt < 16; ++mt) {
            __syncthreads();
            #pragma unroll
            for (int i = 0; i < 4; ++i) {
                int e = tid + i * 256;
                int d = e >> 3, m8 = e & 7;
                *(bf16x8*)(vt + d * LDV + m8 * 8) =
                    *(const bf16x8*)(vtb + (b * D + d) * S + z * 1024 + mt * 64 + m8 * 8);
            }
            __syncthreads();
            #pragma unroll
            for (int kt = 0; kt < 2; ++kt) {
                bf16x8 af;
                int idx0 = mt * 64 + kt * 32 + q16 * 8 + 31 - s * 16 - l15;
                #pragma unroll
                for (int j = 0; j < 8; ++j) af[j] = pw[idx0 + j];
                #pragma unroll
                for (int dt = 0; dt < 4; ++dt) {
                    bf16x8 bv = *(const bf16x8*)(vt + (dh * 64 + dt * 16 + l15) * LDV + kt * 32 + q16 * 8);
                    acc[dt] = __builtin_amdgcn_mfma_f32_16x16x32_bf16(af, bv, acc[dt], 0, 0, 0);
                }
            }
        }
        float* dst = ap + z * BSD;
        const int nrow = n0 + s * 16 + q16 * 4;
        #pragma unroll
        for (int dt = 0; dt < 4; ++dt)
            #pragma unroll
            for (int r = 0; r < 4; ++r)
                dst[(b * S + nrow + r) * D + dh * 64 + dt * 16 + l15] = acc[dt][r];
    }
}

// ---------------------------------------------------------------------------
// Kernel 3 (MFMA): 1024 blocks x 8 rows. Phase A: LN (32 lanes/row) -> h bf16
// LDS. Phase B: h[8][256] @ Wf^T via MFMA (rows 8..15 zeroed), relu+residual.
// ---------------------------------------------------------------------------
__global__ __launch_bounds__(256) void k_final(
    const float* __restrict__ as_part, const float* __restrict__ ap,
    const short* __restrict__ ub, const short* __restrict__ wft,
    const float* __restrict__ gamma, const float* __restrict__ beta,
    const float* __restrict__ bfb,
    const float* __restrict__ x, float* __restrict__ out)
{
    __shared__ short hsb[16 * LDH] __attribute__((aligned(16)));
    const int tid  = threadIdx.x;
    const int row0 = blockIdx.x * 8;

    // zero rows 8..15 (MFMA A-frag padding)
    for (int i = tid; i < 8 * LDH; i += 256) hsb[8 * LDH + i] = 0;

    // ---- Phase A: LN + u-mult, 32 lanes per row ----
    {
        const int row = tid >> 5;            // 0..7
        const int c   = tid & 31;
        float av[8];
        float s1 = 0.f, s2 = 0.f;
        #pragma unroll
        for (int j = 0; j < 8; ++j) {
            int col = c + j * 32;
            float v_;
            if (col < 128) v_ = as_part[(row0 + row) * D + col] + as_part[BSD + (row0 + row) * D + col];
            else           v_ = ap[(row0 + row) * D + col - 128] + ap[BSD + (row0 + row) * D + col - 128];
            av[j] = v_;
            s1 += v_;
            s2 += v_ * v_;
        }
        #pragma unroll
        for (int off = 1; off < 32; off <<= 1) {
            s1 += __shfl_xor(s1, off);
            s2 += __shfl_xor(s2, off);
        }
        float mu  = s1 * (1.f / 256.f);
        float var = s2 * (1.f / 256.f) - mu * mu;
        float rs  = rsqrtf(var + 1e-3f);
        #pragma unroll
        for (int j = 0; j < 8; ++j) {
            int col = c + j * 32;
            float an = (av[j] - mu) * rs * gamma[col] + beta[col];
            float h  = bfs2f(ub[(row0 + row) * D2 + col]) * an;
            hsb[row * LDH + col] = f2bfs(h);
        }
    }
    __syncthreads();

    // ---- Phase B: wave w covers 32 out-cols; only rows 0..7 stored ----
    const int w    = tid >> 6;
    const int lane = tid & 63;
    const int q16  = lane >> 4;
    const int l15  = lane & 15;
    f32x4 o[2];
    o[0] = (f32x4){0.f, 0.f, 0.f, 0.f};
    o[1] = (f32x4){0.f, 0.f, 0.f, 0.f};
    #pragma unroll
    for (int ks = 0; ks < 8; ++ks) {
        bf16x8 af = *(const bf16x8*)(hsb + l15 * LDH + ks * 32 + q16 * 8);
        #pragma unroll
        for (int ci = 0; ci < 2; ++ci) {
            const int ct = w * 2 + ci;
            bf16x8 bfr = *(const bf16x8*)(wft + (ct * 16 + l15) * D2 + ks * 32 + q16 * 8);
            o[ci] = __builtin_amdgcn_mfma_f32_16x16x32_bf16(af, bfr, o[ci], 0, 0, 0);
        }
    }
    if (q16 < 2) {
        #pragma unroll
        for (int ci = 0; ci < 2; ++ci) {
            const int n = (w * 2 + ci) * 16 + l15;
            const float bfv = bfb[n];
            #pragma unroll
            for (int r = 0; r < 4; ++r) {
                const int row = row0 + q16 * 4 + r;
                float oo = o[ci][r] + bfv;
                oo = fmaxf(oo, 0.f);
                oo += x[row * D + n];
                out[row * D + n] = oo;
            }
        }
    }
}

// ---------------------------------------------------------------------------
extern "C" void kernel_launch(void* const* d_in, const int* in_sizes, int n_in,
                              void* d_out, int out_size, void* d_ws, size_t ws_size,
                              hipStream_t stream)
{
    const float* x     = (const float*)d_in[0];
    const float* Wq    = (const float*)d_in[1];
    const float* bq    = (const float*)d_in[2];
    const float* Wk    = (const float*)d_in[3];
    const float* bk    = (const float*)d_in[4];
    const float* Wv    = (const float*)d_in[5];
    const float* bv    = (const float*)d_in[6];
    const float* Wu    = (const float*)d_in[7];
    const float* bu    = (const float*)d_in[8];
    const float* pos_w = (const float*)d_in[9];
    const float* gamma = (const float*)d_in[10];
    const float* beta  = (const float*)d_in[11];
    const float* Wf    = (const float*)d_in[12];
    const float* bfb   = (const float*)d_in[13];
    float* out = (float*)d_out;

    // workspace (~26.2 MB; 28 MB proven safe):
    char* p = (char*)d_ws;
    short* qb      = (short*)p;  p += (size_t)BSD * 2;        // 2 MB bf16 q
    short* kb      = (short*)p;  p += (size_t)BSD * 2;        // 2 MB bf16 k
    short* vtb     = (short*)p;  p += (size_t)BSD * 2;        // 2 MB bf16 v^T [B][D][S]
    short* ubuf    = (short*)p;  p += (size_t)2 * BSD * 2;    // 4 MB bf16 u
    float* as_part = (float*)p;  p += (size_t)2 * BSD * 4;    // 8 MB fp32 self partials x2
    float* ap      = (float*)p;  p += (size_t)2 * BSD * 4;    // 8 MB fp32 pos partials x2
    short* wqt     = (short*)p;  p += (size_t)D * D * 2;      // 32 KB bf16 Wq^T
    short* wkt     = (short*)p;  p += (size_t)D * D * 2;      // 32 KB bf16 Wk^T
    short* wvt     = (short*)p;  p += (size_t)D * D * 2;      // 32 KB bf16 Wv^T
    short* wut     = (short*)p;  p += (size_t)D2 * D * 2;     // 64 KB bf16 Wu^T
    short* wft     = (short*)p;  p += (size_t)D * D2 * 2;     // 64 KB bf16 Wf^T

    k_wt   <<<dim3(448),    256, 0, stream>>>(Wq, Wk, Wv, Wu, Wf, wqt, wkt, wvt, wut, wft);
    k_qkvu <<<dim3(512, 2), 256, 0, stream>>>(x, wqt, wkt, wvt, wut, bq, bk, bv, bu, qb, kb, vtb, ubuf);
    k_mix  <<<dim3(1536),   256, 0, stream>>>(qb, kb, vtb, pos_w, as_part, ap);
    k_final<<<dim3(1024),   256, 0, stream>>>(as_part, ap, ubuf, wft, gamma, beta, bfb, x, out);
}